// Round 1
// baseline (681.833 us; speedup 1.0000x reference)
//
#include <hip/hip_runtime.h>
#include <hip/hip_bf16.h>
#include <cstdint>
#include <cstddef>

#define N_NODES 50000
#define N_EDGES 640000
#define ROWS    100000   // B * N_NODES
#define HID     128
#define OUTD    16
#define AGG_BLOCKS 2048
#define SCAN_BLOCKS 196  // ceil(50000/256)

// ---------- bf16 helpers ----------
__device__ __forceinline__ float bf_lo(uint32_t u){
  union { uint32_t u; float f; } c; c.u = u << 16; return c.f;
}
__device__ __forceinline__ float bf_hi(uint32_t u){
  union { uint32_t u; float f; } c; c.u = u & 0xffff0000u; return c.f;
}
__device__ __forceinline__ uint16_t f2bf(float f){
  union { float f; uint32_t u; } c; c.f = f;
  uint32_t u = c.u;
  uint32_t r = (u + 0x7fffu + ((u >> 16) & 1u)) >> 16;  // RNE
  return (uint16_t)r;
}

typedef __attribute__((ext_vector_type(8))) uint16_t ushort8;

// ---------- edge prep ----------
__global__ void k_init(float* __restrict__ deg, int* __restrict__ counts){
  int i = blockIdx.x * 256 + threadIdx.x;
  if (i < N_NODES){ deg[i] = 1.0f; counts[i] = 0; }  // self-loop weight 1
}

__global__ void k_edge1(const int* __restrict__ ei, const float* __restrict__ ewp,
                        float* __restrict__ ew, float* __restrict__ deg, int* __restrict__ counts){
  int e = blockIdx.x * 256 + threadIdx.x;
  if (e < N_EDGES){
    float w = expf(ewp[e]);
    ew[e] = w;
    int c = ei[N_EDGES + e];
    atomicAdd(&deg[c], w);
    atomicAdd(&counts[c], 1);
  }
}

__global__ void k_dinv(float* __restrict__ deg){
  int i = blockIdx.x * 256 + threadIdx.x;
  if (i < N_NODES) deg[i] = 1.0f / sqrtf(deg[i]);   // deg >= 1 always
}

// ---------- exclusive scan of counts -> row_ptr ----------
__global__ void k_scan_bsum(const int* __restrict__ counts, int* __restrict__ bsum){
  __shared__ int sd[256];
  int tid = threadIdx.x;
  int i = blockIdx.x * 256 + tid;
  sd[tid] = (i < N_NODES) ? counts[i] : 0;
  __syncthreads();
  for (int off = 128; off > 0; off >>= 1){
    if (tid < off) sd[tid] += sd[tid + off];
    __syncthreads();
  }
  if (tid == 0) bsum[blockIdx.x] = sd[0];
}

__global__ void k_scan_excl(int* __restrict__ bsum){
  __shared__ int sd[256];
  int tid = threadIdx.x;
  sd[tid] = (tid < SCAN_BLOCKS) ? bsum[tid] : 0;
  __syncthreads();
  if (tid == 0){
    int run = 0;
    for (int i = 0; i < SCAN_BLOCKS; i++){ int t = sd[i]; sd[i] = run; run += t; }
  }
  __syncthreads();
  if (tid < SCAN_BLOCKS) bsum[tid] = sd[tid];
}

__global__ void k_scan_write(const int* __restrict__ counts, const int* __restrict__ bsum,
                             int* __restrict__ rp){
  __shared__ int sd[256];
  int tid = threadIdx.x;
  int i = blockIdx.x * 256 + tid;
  int v = (i < N_NODES) ? counts[i] : 0;
  sd[tid] = v;
  __syncthreads();
  for (int off = 1; off < 256; off <<= 1){
    int t = (tid >= off) ? sd[tid - off] : 0;
    __syncthreads();
    sd[tid] += t;
    __syncthreads();
  }
  if (i < N_NODES) rp[i] = bsum[blockIdx.x] + sd[tid] - v;
  if (blockIdx.x == 0 && tid == 0) rp[N_NODES] = N_EDGES;
}

__global__ void k_cursor(const int* __restrict__ rp, int* __restrict__ cur){
  int i = blockIdx.x * 256 + threadIdx.x;
  if (i < N_NODES) cur[i] = rp[i];
}

__global__ void k_fill(const int* __restrict__ ei, const float* __restrict__ ew,
                       const float* __restrict__ dinv, int* __restrict__ cur,
                       int* __restrict__ csrc, float* __restrict__ cw){
  int e = blockIdx.x * 256 + threadIdx.x;
  if (e < N_EDGES){
    int r = ei[e];
    int c = ei[N_EDGES + e];
    float nrm = dinv[r] * ew[e] * dinv[c];
    int p = atomicAdd(&cur[c], 1);
    csrc[p] = r;
    cw[p] = nrm;
  }
}

// ---------- GEMM [ROWS,128] @ [128,128] -> bf16, optional per-feature affine on input ----------
template <bool BF16_IN>
__global__ __launch_bounds__(256) void k_gemm128(const void* __restrict__ Xv,
                                                 const float* __restrict__ W,
                                                 const float* __restrict__ sca,
                                                 const float* __restrict__ shf,
                                                 uint16_t* __restrict__ Y){
  __shared__ float xs[64][132];   // +4 pad: 2-way LDS conflicts only (free)
  const int tid = threadIdx.x;
  const int row0 = blockIdx.x * 64;

  // stage 64x128 tile (apply BN affine here if provided)
  for (int idx = tid; idx < 2048; idx += 256){
    int r  = idx >> 5;
    int kc = (idx & 31) << 2;
    int grow = row0 + r;
    float4 v = make_float4(0.f, 0.f, 0.f, 0.f);
    if (grow < ROWS){
      if (BF16_IN){
        const uint32_t* p = (const uint32_t*)Xv + (size_t)grow * 64 + (kc >> 1);
        uint32_t g0 = p[0], g1 = p[1];
        v.x = bf_lo(g0); v.y = bf_hi(g0); v.z = bf_lo(g1); v.w = bf_hi(g1);
      } else {
        v = *((const float4*)((const float*)Xv + (size_t)grow * 128 + kc));
      }
    }
    if (sca){
      float4 s = *((const float4*)(sca + kc));
      float4 t = *((const float4*)(shf + kc));
      v.x = fmaf(v.x, s.x, t.x); v.y = fmaf(v.y, s.y, t.y);
      v.z = fmaf(v.z, s.z, t.z); v.w = fmaf(v.w, s.w, t.w);
    }
    *((float4*)&xs[r][kc]) = v;
  }
  __syncthreads();

  const int tc = tid & 15;     // 16 col-groups of 8
  const int tr = tid >> 4;     // 16 row-groups of 4
  float acc[4][8];
#pragma unroll
  for (int i = 0; i < 4; i++)
#pragma unroll
    for (int j = 0; j < 8; j++) acc[i][j] = 0.f;

  const float* Wp = W + tc * 8;
  for (int k = 0; k < 128; k += 4){
    float4 a[4];
#pragma unroll
    for (int i = 0; i < 4; i++) a[i] = *((const float4*)&xs[tr * 4 + i][k]);
#pragma unroll
    for (int kk = 0; kk < 4; kk++){
      float4 w0 = *((const float4*)(Wp + (k + kk) * 128));
      float4 w1 = *((const float4*)(Wp + (k + kk) * 128 + 4));
      float wv[8] = {w0.x, w0.y, w0.z, w0.w, w1.x, w1.y, w1.z, w1.w};
#pragma unroll
      for (int i = 0; i < 4; i++){
        float av = ((const float*)&a[i])[kk];
#pragma unroll
        for (int j = 0; j < 8; j++) acc[i][j] = fmaf(av, wv[j], acc[i][j]);
      }
    }
  }

#pragma unroll
  for (int i = 0; i < 4; i++){
    int grow = row0 + tr * 4 + i;
    if (grow < ROWS){
      ushort8 t8;
#pragma unroll
      for (int j = 0; j < 8; j++) t8[j] = f2bf(acc[i][j]);
      *((ushort8*)(Y + (size_t)grow * 128 + tc * 8)) = t8;
    }
  }
}

// ---------- aggregation: h[b,i] = relu( selfnorm*xw[b,i] + sum_e w_e*xw[b,src_e] + bias ), + BN partial stats ----------
__global__ __launch_bounds__(256) void k_agg(const uint16_t* __restrict__ XW,
                                             const int* __restrict__ rp,
                                             const int* __restrict__ csrc,
                                             const float* __restrict__ cw,
                                             const float* __restrict__ dinv,
                                             const float* __restrict__ bias,
                                             uint16_t* __restrict__ H,
                                             float* __restrict__ psum,
                                             float* __restrict__ pssq){
  __shared__ float lsum[128];
  __shared__ float lssq[128];
  const int tid = threadIdx.x;
  if (tid < 128){ lsum[tid] = 0.f; lssq[tid] = 0.f; }
  __syncthreads();

  const int lane = tid & 63;
  const int wid  = tid >> 6;
  const int gw   = blockIdx.x * 4 + wid;
  const int nw   = gridDim.x * 4;
  const uint32_t* Xu = (const uint32_t*)XW;   // one row = 64 packed bf16x2
  uint32_t* Hu = (uint32_t*)H;
  const int f0 = lane * 2;
  const float b0 = bias[f0], b1 = bias[f0 + 1];
  float ts0 = 0.f, ts1 = 0.f, tq0 = 0.f, tq1 = 0.f;

  for (int node = gw; node < N_NODES; node += nw){
    const float di = dinv[node];
    const float sn = di * di;
    const int e0 = rp[node], e1 = rp[node + 1];
    uint32_t s0 = Xu[(size_t)node * 64 + lane];
    uint32_t s1 = Xu[(size_t)(N_NODES + node) * 64 + lane];
    float a0x = sn * bf_lo(s0), a0y = sn * bf_hi(s0);
    float a1x = sn * bf_lo(s1), a1y = sn * bf_hi(s1);
    for (int e = e0; e < e1; e++){
      int src = csrc[e];
      float w = cw[e];
      uint32_t g0 = Xu[(size_t)src * 64 + lane];
      uint32_t g1 = Xu[(size_t)(N_NODES + src) * 64 + lane];
      a0x = fmaf(w, bf_lo(g0), a0x); a0y = fmaf(w, bf_hi(g0), a0y);
      a1x = fmaf(w, bf_lo(g1), a1x); a1y = fmaf(w, bf_hi(g1), a1y);
    }
    a0x = fmaxf(a0x + b0, 0.f); a0y = fmaxf(a0y + b1, 0.f);
    a1x = fmaxf(a1x + b0, 0.f); a1y = fmaxf(a1y + b1, 0.f);
    Hu[(size_t)node * 64 + lane]             = (uint32_t)f2bf(a0x) | ((uint32_t)f2bf(a0y) << 16);
    Hu[(size_t)(N_NODES + node) * 64 + lane] = (uint32_t)f2bf(a1x) | ((uint32_t)f2bf(a1y) << 16);
    ts0 += a0x + a1x; ts1 += a0y + a1y;
    tq0 += a0x * a0x + a1x * a1x; tq1 += a0y * a0y + a1y * a1y;
  }

  atomicAdd(&lsum[f0],     ts0); atomicAdd(&lsum[f0 + 1], ts1);
  atomicAdd(&lssq[f0],     tq0); atomicAdd(&lssq[f0 + 1], tq1);
  __syncthreads();
  if (tid < 128){
    psum[(size_t)blockIdx.x * 128 + tid] = lsum[tid];
    pssq[(size_t)blockIdx.x * 128 + tid] = lssq[tid];
  }
}

// ---------- BN finalize: s = g*rstd, t = be - mu*s ----------
__global__ __launch_bounds__(1024) void k_bnfin(const float* __restrict__ psum,
                                                const float* __restrict__ pssq,
                                                const float* __restrict__ gamma,
                                                const float* __restrict__ beta,
                                                float* __restrict__ sca,
                                                float* __restrict__ shf){
  __shared__ float ss[8][128];
  __shared__ float sq[8][128];
  const int tid = threadIdx.x;
  const int f  = tid & 127;
  const int sl = tid >> 7;
  float s = 0.f, q = 0.f;
  for (int b = sl; b < AGG_BLOCKS; b += 8){
    s += psum[(size_t)b * 128 + f];
    q += pssq[(size_t)b * 128 + f];
  }
  ss[sl][f] = s; sq[sl][f] = q;
  __syncthreads();
  if (tid < 128){
    float S = 0.f, Q = 0.f;
#pragma unroll
    for (int i = 0; i < 8; i++){ S += ss[i][tid]; Q += sq[i][tid]; }
    const float inv = 1.0f / (float)ROWS;
    float mu = S * inv;
    float var = fmaxf(Q * inv - mu * mu, 0.f);
    float rstd = 1.0f / sqrtf(var + 1e-5f);
    float sc = gamma[tid] * rstd;
    sca[tid] = sc;
    shf[tid] = fmaf(-mu, sc, beta[tid]);
  }
}

// ---------- classifier: out = (h*s+t) @ Wc + bc ----------
__global__ __launch_bounds__(256) void k_cls(const uint16_t* __restrict__ H,
                                             const float* __restrict__ sca,
                                             const float* __restrict__ shf,
                                             const float* __restrict__ Wc,
                                             const float* __restrict__ bc,
                                             float* __restrict__ out){
  const int t = blockIdx.x * 256 + threadIdx.x;
  if (t >= ROWS * OUTD) return;
  const int oc  = t & 15;
  const int row = t >> 4;
  const uint32_t* hp = (const uint32_t*)H + (size_t)row * 64;
  float acc = bc[oc];
#pragma unroll
  for (int k = 0; k < 128; k += 2){
    uint32_t g = hp[k >> 1];
    float h0 = fmaf(bf_lo(g), sca[k],     shf[k]);
    float h1 = fmaf(bf_hi(g), sca[k + 1], shf[k + 1]);
    acc = fmaf(h0, Wc[k * 16 + oc],       acc);
    acc = fmaf(h1, Wc[(k + 1) * 16 + oc], acc);
  }
  out[t] = acc;
}

// ---------- launch ----------
extern "C" void kernel_launch(void* const* d_in, const int* in_sizes, int n_in,
                              void* d_out, int out_size, void* d_ws, size_t ws_size,
                              hipStream_t stream){
  const float* x   = (const float*)d_in[0];
  const int*   ei  = (const int*)d_in[1];
  const float* ewp = (const float*)d_in[2];
  const float* W1  = (const float*)d_in[3];
  const float* b1  = (const float*)d_in[4];
  const float* W2  = (const float*)d_in[5];
  const float* b2  = (const float*)d_in[6];
  const float* g1  = (const float*)d_in[7];
  const float* be1 = (const float*)d_in[8];
  const float* g2  = (const float*)d_in[9];
  const float* be2 = (const float*)d_in[10];
  const float* Wc  = (const float*)d_in[11];
  const float* bc  = (const float*)d_in[12];
  float* out = (float*)d_out;

  char* wsb = (char*)d_ws;
  size_t off = 0;
  auto give = [&](size_t bytes) -> void* {
    void* p = wsb + off;
    off = (off + bytes + 255) & ~(size_t)255;
    return p;
  };
  uint16_t* XW  = (uint16_t*)give((size_t)ROWS * 128 * 2);
  uint16_t* Hb  = (uint16_t*)give((size_t)ROWS * 128 * 2);
  float* EW     = (float*)give((size_t)N_EDGES * 4);
  float* DEG    = (float*)give((size_t)N_NODES * 4);   // becomes dinv in-place
  int*   CSRC   = (int*)give((size_t)N_EDGES * 4);
  float* CW     = (float*)give((size_t)N_EDGES * 4);
  int*   COUNTS = (int*)give((size_t)N_NODES * 4);
  int*   RP     = (int*)give((size_t)(N_NODES + 1) * 4);
  int*   CUR    = (int*)give((size_t)N_NODES * 4);
  int*   BSUM   = (int*)give(1024);
  float* PSUM   = (float*)give((size_t)AGG_BLOCKS * 128 * 4);
  float* PSSQ   = (float*)give((size_t)AGG_BLOCKS * 128 * 4);
  float* SCA1   = (float*)give(512);
  float* SHF1   = (float*)give(512);
  float* SCA2   = (float*)give(512);
  float* SHF2   = (float*)give(512);
  (void)ws_size; (void)n_in; (void)in_sizes; (void)out_size;

  const int nb_nodes = (N_NODES + 255) / 256;   // 196
  const int nb_edges = (N_EDGES + 255) / 256;   // 2500
  const int nb_gemm  = (ROWS + 63) / 64;        // 1563
  const int nb_cls   = (ROWS * OUTD + 255) / 256; // 6250

  k_init<<<nb_nodes, 256, 0, stream>>>(DEG, COUNTS);
  k_edge1<<<nb_edges, 256, 0, stream>>>(ei, ewp, EW, DEG, COUNTS);
  k_dinv<<<nb_nodes, 256, 0, stream>>>(DEG);
  k_scan_bsum<<<SCAN_BLOCKS, 256, 0, stream>>>(COUNTS, BSUM);
  k_scan_excl<<<1, 256, 0, stream>>>(BSUM);
  k_scan_write<<<SCAN_BLOCKS, 256, 0, stream>>>(COUNTS, BSUM, RP);
  k_cursor<<<nb_nodes, 256, 0, stream>>>(RP, CUR);
  k_fill<<<nb_edges, 256, 0, stream>>>(ei, EW, DEG, CUR, CSRC, CW);

  // layer 1
  k_gemm128<false><<<nb_gemm, 256, 0, stream>>>(x, W1, nullptr, nullptr, XW);
  k_agg<<<AGG_BLOCKS, 256, 0, stream>>>(XW, RP, CSRC, CW, DEG, b1, Hb, PSUM, PSSQ);
  k_bnfin<<<1, 1024, 0, stream>>>(PSUM, PSSQ, g1, be1, SCA1, SHF1);

  // layer 2
  k_gemm128<true><<<nb_gemm, 256, 0, stream>>>(Hb, W2, SCA1, SHF1, XW);
  k_agg<<<AGG_BLOCKS, 256, 0, stream>>>(XW, RP, CSRC, CW, DEG, b2, Hb, PSUM, PSSQ);
  k_bnfin<<<1, 1024, 0, stream>>>(PSUM, PSSQ, g2, be2, SCA2, SHF2);

  // classifier
  k_cls<<<nb_cls, 256, 0, stream>>>(Hb, SCA2, SHF2, Wc, bc, out);
}

// Round 2
// 553.022 us; speedup vs baseline: 1.2329x; 1.2329x over previous
//
#include <hip/hip_runtime.h>
#include <hip/hip_bf16.h>
#include <cstdint>
#include <cstddef>

#define N_NODES 50000
#define N_EDGES 640000
#define ROWS    100000   // B * N_NODES
#define HID     128
#define OUTD    16
#define AGG_BLOCKS 2048
#define MID_BLOCKS 32
#define SCAN_BLOCKS 196  // ceil(50000/256)

// ---------- bf16 helpers ----------
__device__ __forceinline__ float bf_lo(uint32_t u){
  union { uint32_t u; float f; } c; c.u = u << 16; return c.f;
}
__device__ __forceinline__ float bf_hi(uint32_t u){
  union { uint32_t u; float f; } c; c.u = u & 0xffff0000u; return c.f;
}
__device__ __forceinline__ uint16_t f2bf(float f){
  union { float f; uint32_t u; } c; c.f = f;
  uint32_t u = c.u;
  uint32_t r = (u + 0x7fffu + ((u >> 16) & 1u)) >> 16;  // RNE
  return (uint16_t)r;
}

typedef __attribute__((ext_vector_type(8))) uint16_t ushort8;

// ---------- edge prep ----------
__global__ void k_init(float* __restrict__ deg, int* __restrict__ counts){
  int i = blockIdx.x * 256 + threadIdx.x;
  if (i < N_NODES){ deg[i] = 1.0f; counts[i] = 0; }  // self-loop weight 1
}

__global__ void k_edge1(const int* __restrict__ ei, const float* __restrict__ ewp,
                        float* __restrict__ ew, float* __restrict__ deg, int* __restrict__ counts){
  int e = blockIdx.x * 256 + threadIdx.x;
  if (e < N_EDGES){
    float w = expf(ewp[e]);
    ew[e] = w;
    int c = ei[N_EDGES + e];
    atomicAdd(&deg[c], w);
    atomicAdd(&counts[c], 1);
  }
}

// scan block-sums + dinv fused (same 196-block grid; deg finalized by k_edge1)
__global__ void k_scan_bsum(const int* __restrict__ counts, int* __restrict__ bsum,
                            float* __restrict__ deg){
  __shared__ int sd[256];
  int tid = threadIdx.x;
  int i = blockIdx.x * 256 + tid;
  if (i < N_NODES) deg[i] = 1.0f / sqrtf(deg[i]);   // deg >= 1 always
  sd[tid] = (i < N_NODES) ? counts[i] : 0;
  __syncthreads();
  for (int off = 128; off > 0; off >>= 1){
    if (tid < off) sd[tid] += sd[tid + off];
    __syncthreads();
  }
  if (tid == 0) bsum[blockIdx.x] = sd[0];
}

__global__ void k_scan_excl(int* __restrict__ bsum){
  __shared__ int sd[256];
  int tid = threadIdx.x;
  sd[tid] = (tid < SCAN_BLOCKS) ? bsum[tid] : 0;
  __syncthreads();
  if (tid == 0){
    int run = 0;
    for (int i = 0; i < SCAN_BLOCKS; i++){ int t = sd[i]; sd[i] = run; run += t; }
  }
  __syncthreads();
  if (tid < SCAN_BLOCKS) bsum[tid] = sd[tid];
}

__global__ void k_scan_write(const int* __restrict__ counts, const int* __restrict__ bsum,
                             int* __restrict__ rp, int* __restrict__ cur){
  __shared__ int sd[256];
  int tid = threadIdx.x;
  int i = blockIdx.x * 256 + tid;
  int v = (i < N_NODES) ? counts[i] : 0;
  sd[tid] = v;
  __syncthreads();
  for (int off = 1; off < 256; off <<= 1){
    int t = (tid >= off) ? sd[tid - off] : 0;
    __syncthreads();
    sd[tid] += t;
    __syncthreads();
  }
  if (i < N_NODES){
    int r = bsum[blockIdx.x] + sd[tid] - v;
    rp[i] = r;
    cur[i] = r;
  }
  if (blockIdx.x == 0 && tid == 0) rp[N_NODES] = N_EDGES;
}

__global__ void k_fill(const int* __restrict__ ei, const float* __restrict__ ew,
                       const float* __restrict__ dinv, int* __restrict__ cur,
                       int* __restrict__ csrc, float* __restrict__ cw){
  int e = blockIdx.x * 256 + threadIdx.x;
  if (e < N_EDGES){
    int r = ei[e];
    int c = ei[N_EDGES + e];
    float nrm = dinv[r] * ew[e] * dinv[c];
    int p = atomicAdd(&cur[c], 1);
    csrc[p] = r;
    cw[p] = nrm;
  }
}

// ---------- GEMM [ROWS,128] @ [128,128] -> bf16, optional per-feature affine on input ----------
template <bool BF16_IN>
__global__ __launch_bounds__(256) void k_gemm128(const void* __restrict__ Xv,
                                                 const float* __restrict__ W,
                                                 const float* __restrict__ sca,
                                                 const float* __restrict__ shf,
                                                 uint16_t* __restrict__ Y){
  __shared__ float xs[64][132];   // +4 pad: 2-way LDS conflicts only (free)
  const int tid = threadIdx.x;
  const int row0 = blockIdx.x * 64;

  // stage 64x128 tile (apply BN affine here if provided)
  for (int idx = tid; idx < 2048; idx += 256){
    int r  = idx >> 5;
    int kc = (idx & 31) << 2;
    int grow = row0 + r;
    float4 v = make_float4(0.f, 0.f, 0.f, 0.f);
    if (grow < ROWS){
      if (BF16_IN){
        const uint32_t* p = (const uint32_t*)Xv + (size_t)grow * 64 + (kc >> 1);
        uint32_t g0 = p[0], g1 = p[1];
        v.x = bf_lo(g0); v.y = bf_hi(g0); v.z = bf_lo(g1); v.w = bf_hi(g1);
      } else {
        v = *((const float4*)((const float*)Xv + (size_t)grow * 128 + kc));
      }
    }
    if (sca){
      float4 s = *((const float4*)(sca + kc));
      float4 t = *((const float4*)(shf + kc));
      v.x = fmaf(v.x, s.x, t.x); v.y = fmaf(v.y, s.y, t.y);
      v.z = fmaf(v.z, s.z, t.z); v.w = fmaf(v.w, s.w, t.w);
    }
    *((float4*)&xs[r][kc]) = v;
  }
  __syncthreads();

  const int tc = tid & 15;     // 16 col-groups of 8
  const int tr = tid >> 4;     // 16 row-groups of 4
  float acc[4][8];
#pragma unroll
  for (int i = 0; i < 4; i++)
#pragma unroll
    for (int j = 0; j < 8; j++) acc[i][j] = 0.f;

  const float* Wp = W + tc * 8;
  for (int k = 0; k < 128; k += 4){
    float4 a[4];
#pragma unroll
    for (int i = 0; i < 4; i++) a[i] = *((const float4*)&xs[tr * 4 + i][k]);
#pragma unroll
    for (int kk = 0; kk < 4; kk++){
      float4 w0 = *((const float4*)(Wp + (k + kk) * 128));
      float4 w1 = *((const float4*)(Wp + (k + kk) * 128 + 4));
      float wv[8] = {w0.x, w0.y, w0.z, w0.w, w1.x, w1.y, w1.z, w1.w};
#pragma unroll
      for (int i = 0; i < 4; i++){
        float av = ((const float*)&a[i])[kk];
#pragma unroll
        for (int j = 0; j < 8; j++) acc[i][j] = fmaf(av, wv[j], acc[i][j]);
      }
    }
  }

#pragma unroll
  for (int i = 0; i < 4; i++){
    int grow = row0 + tr * 4 + i;
    if (grow < ROWS){
      ushort8 t8;
#pragma unroll
      for (int j = 0; j < 8; j++) t8[j] = f2bf(acc[i][j]);
      *((ushort8*)(Y + (size_t)grow * 128 + tc * 8)) = t8;
    }
  }
}

// ---------- aggregation: h[b,i] = relu( selfnorm*xw[b,i] + sum_e w_e*xw[b,src_e] + bias ), + BN partial stats ----------
__global__ __launch_bounds__(256) void k_agg(const uint16_t* __restrict__ XW,
                                             const int* __restrict__ rp,
                                             const int* __restrict__ csrc,
                                             const float* __restrict__ cw,
                                             const float* __restrict__ dinv,
                                             const float* __restrict__ bias,
                                             uint16_t* __restrict__ H,
                                             float* __restrict__ psum,
                                             float* __restrict__ pssq){
  __shared__ float lsum[128];
  __shared__ float lssq[128];
  const int tid = threadIdx.x;
  if (tid < 128){ lsum[tid] = 0.f; lssq[tid] = 0.f; }
  __syncthreads();

  const int lane = tid & 63;
  const int wid  = tid >> 6;
  const int gw   = blockIdx.x * 4 + wid;
  const int nw   = gridDim.x * 4;
  const uint32_t* Xu = (const uint32_t*)XW;   // one row = 64 packed bf16x2
  uint32_t* Hu = (uint32_t*)H;
  const int f0 = lane * 2;
  const float b0 = bias[f0], b1 = bias[f0 + 1];
  float ts0 = 0.f, ts1 = 0.f, tq0 = 0.f, tq1 = 0.f;

  for (int node = gw; node < N_NODES; node += nw){
    const float di = dinv[node];
    const float sn = di * di;
    const int e0 = rp[node], e1 = rp[node + 1];
    uint32_t s0 = Xu[(size_t)node * 64 + lane];
    uint32_t s1 = Xu[(size_t)(N_NODES + node) * 64 + lane];
    float a0x = sn * bf_lo(s0), a0y = sn * bf_hi(s0);
    float a1x = sn * bf_lo(s1), a1y = sn * bf_hi(s1);
    for (int e = e0; e < e1; e++){
      int src = csrc[e];
      float w = cw[e];
      uint32_t g0 = Xu[(size_t)src * 64 + lane];
      uint32_t g1 = Xu[(size_t)(N_NODES + src) * 64 + lane];
      a0x = fmaf(w, bf_lo(g0), a0x); a0y = fmaf(w, bf_hi(g0), a0y);
      a1x = fmaf(w, bf_lo(g1), a1x); a1y = fmaf(w, bf_hi(g1), a1y);
    }
    a0x = fmaxf(a0x + b0, 0.f); a0y = fmaxf(a0y + b1, 0.f);
    a1x = fmaxf(a1x + b0, 0.f); a1y = fmaxf(a1y + b1, 0.f);
    Hu[(size_t)node * 64 + lane]             = (uint32_t)f2bf(a0x) | ((uint32_t)f2bf(a0y) << 16);
    Hu[(size_t)(N_NODES + node) * 64 + lane] = (uint32_t)f2bf(a1x) | ((uint32_t)f2bf(a1y) << 16);
    ts0 += a0x + a1x; ts1 += a0y + a1y;
    tq0 += a0x * a0x + a1x * a1x; tq1 += a0y * a0y + a1y * a1y;
  }

  atomicAdd(&lsum[f0],     ts0); atomicAdd(&lsum[f0 + 1], ts1);
  atomicAdd(&lssq[f0],     tq0); atomicAdd(&lssq[f0 + 1], tq1);
  __syncthreads();
  if (tid < 128){
    psum[(size_t)blockIdx.x * 128 + tid] = lsum[tid];
    pssq[(size_t)blockIdx.x * 128 + tid] = lssq[tid];
  }
}

// ---------- BN mid-reduction: 2048 partial rows -> 32 partial rows (parallel across CUs) ----------
__global__ __launch_bounds__(256) void k_bnmid(const float* __restrict__ psum,
                                               const float* __restrict__ pssq,
                                               float* __restrict__ msum,
                                               float* __restrict__ mssq){
  __shared__ float ss[2][128];
  __shared__ float sq[2][128];
  const int tid = threadIdx.x;
  const int f  = tid & 127;
  const int sl = tid >> 7;                       // 0 or 1
  const int rows_per = AGG_BLOCKS / MID_BLOCKS;  // 64
  const int base = blockIdx.x * rows_per;
  float s = 0.f, q = 0.f;
  for (int r = base + sl; r < base + rows_per; r += 2){
    s += psum[(size_t)r * 128 + f];
    q += pssq[(size_t)r * 128 + f];
  }
  ss[sl][f] = s; sq[sl][f] = q;
  __syncthreads();
  if (tid < 128){
    msum[(size_t)blockIdx.x * 128 + tid] = ss[0][tid] + ss[1][tid];
    mssq[(size_t)blockIdx.x * 128 + tid] = sq[0][tid] + sq[1][tid];
  }
}

// ---------- BN finalize: s = g*rstd, t = be - mu*s ----------
__global__ __launch_bounds__(128) void k_bnfin(const float* __restrict__ msum,
                                               const float* __restrict__ mssq,
                                               const float* __restrict__ gamma,
                                               const float* __restrict__ beta,
                                               float* __restrict__ sca,
                                               float* __restrict__ shf){
  const int f = threadIdx.x;   // 128 threads
  float S = 0.f, Q = 0.f;
#pragma unroll
  for (int b = 0; b < MID_BLOCKS; b++){
    S += msum[(size_t)b * 128 + f];
    Q += mssq[(size_t)b * 128 + f];
  }
  const float inv = 1.0f / (float)ROWS;
  float mu = S * inv;
  float var = fmaxf(Q * inv - mu * mu, 0.f);
  float rstd = 1.0f / sqrtf(var + 1e-5f);
  float sc = gamma[f] * rstd;
  sca[f] = sc;
  shf[f] = fmaf(-mu, sc, beta[f]);
}

// ---------- classifier: out = (h*s+t) @ Wc + bc ----------
__global__ __launch_bounds__(256) void k_cls(const uint16_t* __restrict__ H,
                                             const float* __restrict__ sca,
                                             const float* __restrict__ shf,
                                             const float* __restrict__ Wc,
                                             const float* __restrict__ bc,
                                             float* __restrict__ out){
  const int t = blockIdx.x * 256 + threadIdx.x;
  if (t >= ROWS * OUTD) return;
  const int oc  = t & 15;
  const int row = t >> 4;
  const uint32_t* hp = (const uint32_t*)H + (size_t)row * 64;
  float acc = bc[oc];
#pragma unroll
  for (int k = 0; k < 128; k += 2){
    uint32_t g = hp[k >> 1];
    float h0 = fmaf(bf_lo(g), sca[k],     shf[k]);
    float h1 = fmaf(bf_hi(g), sca[k + 1], shf[k + 1]);
    acc = fmaf(h0, Wc[k * 16 + oc],       acc);
    acc = fmaf(h1, Wc[(k + 1) * 16 + oc], acc);
  }
  out[t] = acc;
}

// ---------- launch ----------
extern "C" void kernel_launch(void* const* d_in, const int* in_sizes, int n_in,
                              void* d_out, int out_size, void* d_ws, size_t ws_size,
                              hipStream_t stream){
  const float* x   = (const float*)d_in[0];
  const int*   ei  = (const int*)d_in[1];
  const float* ewp = (const float*)d_in[2];
  const float* W1  = (const float*)d_in[3];
  const float* b1  = (const float*)d_in[4];
  const float* W2  = (const float*)d_in[5];
  const float* b2  = (const float*)d_in[6];
  const float* g1  = (const float*)d_in[7];
  const float* be1 = (const float*)d_in[8];
  const float* g2  = (const float*)d_in[9];
  const float* be2 = (const float*)d_in[10];
  const float* Wc  = (const float*)d_in[11];
  const float* bc  = (const float*)d_in[12];
  float* out = (float*)d_out;

  char* wsb = (char*)d_ws;
  size_t off = 0;
  auto give = [&](size_t bytes) -> void* {
    void* p = wsb + off;
    off = (off + bytes + 255) & ~(size_t)255;
    return p;
  };
  uint16_t* XW  = (uint16_t*)give((size_t)ROWS * 128 * 2);
  uint16_t* Hb  = (uint16_t*)give((size_t)ROWS * 128 * 2);
  float* EW     = (float*)give((size_t)N_EDGES * 4);
  float* DEG    = (float*)give((size_t)N_NODES * 4);   // becomes dinv in-place
  int*   CSRC   = (int*)give((size_t)N_EDGES * 4);
  float* CW     = (float*)give((size_t)N_EDGES * 4);
  int*   COUNTS = (int*)give((size_t)N_NODES * 4);
  int*   RP     = (int*)give((size_t)(N_NODES + 1) * 4);
  int*   CUR    = (int*)give((size_t)N_NODES * 4);
  int*   BSUM   = (int*)give(1024);
  float* PSUM   = (float*)give((size_t)AGG_BLOCKS * 128 * 4);
  float* PSSQ   = (float*)give((size_t)AGG_BLOCKS * 128 * 4);
  float* MSUM   = (float*)give((size_t)MID_BLOCKS * 128 * 4);
  float* MSSQ   = (float*)give((size_t)MID_BLOCKS * 128 * 4);
  float* SCA1   = (float*)give(512);
  float* SHF1   = (float*)give(512);
  float* SCA2   = (float*)give(512);
  float* SHF2   = (float*)give(512);
  (void)ws_size; (void)n_in; (void)in_sizes; (void)out_size;

  const int nb_nodes = (N_NODES + 255) / 256;   // 196
  const int nb_edges = (N_EDGES + 255) / 256;   // 2500
  const int nb_gemm  = (ROWS + 63) / 64;        // 1563
  const int nb_cls   = (ROWS * OUTD + 255) / 256; // 6250

  k_init<<<nb_nodes, 256, 0, stream>>>(DEG, COUNTS);
  k_edge1<<<nb_edges, 256, 0, stream>>>(ei, ewp, EW, DEG, COUNTS);
  k_scan_bsum<<<SCAN_BLOCKS, 256, 0, stream>>>(COUNTS, BSUM, DEG);
  k_scan_excl<<<1, 256, 0, stream>>>(BSUM);
  k_scan_write<<<SCAN_BLOCKS, 256, 0, stream>>>(COUNTS, BSUM, RP, CUR);
  k_fill<<<nb_edges, 256, 0, stream>>>(ei, EW, DEG, CUR, CSRC, CW);

  // layer 1
  k_gemm128<false><<<nb_gemm, 256, 0, stream>>>(x, W1, nullptr, nullptr, XW);
  k_agg<<<AGG_BLOCKS, 256, 0, stream>>>(XW, RP, CSRC, CW, DEG, b1, Hb, PSUM, PSSQ);
  k_bnmid<<<MID_BLOCKS, 256, 0, stream>>>(PSUM, PSSQ, MSUM, MSSQ);
  k_bnfin<<<1, 128, 0, stream>>>(MSUM, MSSQ, g1, be1, SCA1, SHF1);

  // layer 2
  k_gemm128<true><<<nb_gemm, 256, 0, stream>>>(Hb, W2, SCA1, SHF1, XW);
  k_agg<<<AGG_BLOCKS, 256, 0, stream>>>(XW, RP, CSRC, CW, DEG, b2, Hb, PSUM, PSSQ);
  k_bnmid<<<MID_BLOCKS, 256, 0, stream>>>(PSUM, PSSQ, MSUM, MSSQ);
  k_bnfin<<<1, 128, 0, stream>>>(MSUM, MSSQ, g2, be2, SCA2, SHF2);

  // classifier
  k_cls<<<nb_cls, 256, 0, stream>>>(Hb, SCA2, SHF2, Wc, bc, out);
}

// Round 3
// 399.688 us; speedup vs baseline: 1.7059x; 1.3836x over previous
//
#include <hip/hip_runtime.h>
#include <hip/hip_bf16.h>
#include <cstdint>
#include <cstddef>

#define N_NODES 50000
#define N_EDGES 640000
#define ROWS    100000   // B * N_NODES
#define HID     128
#define OUTD    16
#define AGG_BLOCKS 2048
#define MID_BLOCKS 32
#define SCAN_BLOCKS 196  // ceil(50000/256)
#define GEMM_BLOCKS 512
#define GEMM_TILES  (ROWS / 16)   // 6250

// ---------- types ----------
typedef __attribute__((ext_vector_type(8))) uint16_t ushort8;
typedef __attribute__((ext_vector_type(8))) __bf16   bf16x8;
typedef __attribute__((ext_vector_type(4))) float    floatx4;

union FragU { ushort8 u; bf16x8 b; };

// ---------- bf16 helpers ----------
__device__ __forceinline__ float bf_lo(uint32_t u){
  union { uint32_t u; float f; } c; c.u = u << 16; return c.f;
}
__device__ __forceinline__ float bf_hi(uint32_t u){
  union { uint32_t u; float f; } c; c.u = u & 0xffff0000u; return c.f;
}
__device__ __forceinline__ uint16_t f2bf(float f){
  union { float f; uint32_t u; } c; c.f = f;
  uint32_t u = c.u;
  uint32_t r = (u + 0x7fffu + ((u >> 16) & 1u)) >> 16;  // RNE
  return (uint16_t)r;
}

// ---------- edge prep ----------
__global__ void k_init(float* __restrict__ deg, int* __restrict__ counts){
  int i = blockIdx.x * 256 + threadIdx.x;
  if (i < N_NODES){ deg[i] = 1.0f; counts[i] = 0; }  // self-loop weight 1
}

__global__ void k_edge1(const int* __restrict__ ei, const float* __restrict__ ewp,
                        float* __restrict__ ew, float* __restrict__ deg, int* __restrict__ counts){
  int e = blockIdx.x * 256 + threadIdx.x;
  if (e < N_EDGES){
    float w = expf(ewp[e]);
    ew[e] = w;
    int c = ei[N_EDGES + e];
    atomicAdd(&deg[c], w);
    atomicAdd(&counts[c], 1);
  }
}

// scan block-sums + dinv fused
__global__ void k_scan_bsum(const int* __restrict__ counts, int* __restrict__ bsum,
                            float* __restrict__ deg){
  __shared__ int sd[256];
  int tid = threadIdx.x;
  int i = blockIdx.x * 256 + tid;
  if (i < N_NODES) deg[i] = 1.0f / sqrtf(deg[i]);   // deg >= 1 always
  sd[tid] = (i < N_NODES) ? counts[i] : 0;
  __syncthreads();
  for (int off = 128; off > 0; off >>= 1){
    if (tid < off) sd[tid] += sd[tid + off];
    __syncthreads();
  }
  if (tid == 0) bsum[blockIdx.x] = sd[0];
}

__global__ void k_scan_excl(int* __restrict__ bsum){
  __shared__ int sd[256];
  int tid = threadIdx.x;
  sd[tid] = (tid < SCAN_BLOCKS) ? bsum[tid] : 0;
  __syncthreads();
  if (tid == 0){
    int run = 0;
    for (int i = 0; i < SCAN_BLOCKS; i++){ int t = sd[i]; sd[i] = run; run += t; }
  }
  __syncthreads();
  if (tid < SCAN_BLOCKS) bsum[tid] = sd[tid];
}

__global__ void k_scan_write(const int* __restrict__ counts, const int* __restrict__ bsum,
                             int* __restrict__ rp, int* __restrict__ cur){
  __shared__ int sd[256];
  int tid = threadIdx.x;
  int i = blockIdx.x * 256 + tid;
  int v = (i < N_NODES) ? counts[i] : 0;
  sd[tid] = v;
  __syncthreads();
  for (int off = 1; off < 256; off <<= 1){
    int t = (tid >= off) ? sd[tid - off] : 0;
    __syncthreads();
    sd[tid] += t;
    __syncthreads();
  }
  if (i < N_NODES){
    int r = bsum[blockIdx.x] + sd[tid] - v;
    rp[i] = r;
    cur[i] = r;
  }
  if (blockIdx.x == 0 && tid == 0) rp[N_NODES] = N_EDGES;
}

__global__ void k_fill(const int* __restrict__ ei, const float* __restrict__ ew,
                       const float* __restrict__ dinv, int* __restrict__ cur,
                       int* __restrict__ csrc, float* __restrict__ cw){
  int e = blockIdx.x * 256 + threadIdx.x;
  if (e < N_EDGES){
    int r = ei[e];
    int c = ei[N_EDGES + e];
    float nrm = dinv[r] * ew[e] * dinv[c];
    int p = atomicAdd(&cur[c], 1);
    csrc[p] = r;
    cw[p] = nrm;
  }
}

// ---------- weight packing into MFMA B-fragment layout ----------
// B-frag for 16x16x32: lane L holds col n=L&15, k = (L>>4)*8 + j (j=0..7 contiguous)
// Wpack[((c*4+s)*64+L)*8+j] = scale(k)*W[k][16c+n],  k = 32s+(L>>4)*8+j
__global__ void k_wpack(const float* __restrict__ W, const float* __restrict__ sca,
                        uint16_t* __restrict__ WP){
  int t = blockIdx.x * 256 + threadIdx.x;  // 0..2047 (8 blocks)
  int L = t & 63;
  int s = (t >> 6) & 3;
  int c = t >> 8;
  int n = c * 16 + (L & 15);
  int k0 = s * 32 + (L >> 4) * 8;
  ushort8 r;
#pragma unroll
  for (int j = 0; j < 8; j++){
    float w = W[(size_t)(k0 + j) * HID + n];
    if (sca) w *= sca[k0 + j];
    r[j] = f2bf(w);
  }
  *((ushort8*)(WP + (size_t)t * 8)) = r;
}

// classifier weights: 1 col-tile
__global__ void k_wpackc(const float* __restrict__ Wc, const float* __restrict__ sca,
                         uint16_t* __restrict__ WPC){
  int t = threadIdx.x;          // 256
  int L = t & 63;
  int s = t >> 6;
  int n = L & 15;
  int k0 = s * 32 + (L >> 4) * 8;
  ushort8 r;
#pragma unroll
  for (int j = 0; j < 8; j++)
    r[j] = f2bf(sca[k0 + j] * Wc[(size_t)(k0 + j) * OUTD + n]);
  *((ushort8*)(WPC + (size_t)t * 8)) = r;
}

// cv[j] = sum_k shf[k]*W[k*stride+j] (+ bias[j])
__global__ void k_cvec(const float* __restrict__ shf, const float* __restrict__ W,
                       const float* __restrict__ bias, float* __restrict__ cv, int ncol, int stride){
  int j = threadIdx.x;
  if (j < ncol){
    float a = bias ? bias[j] : 0.f;
    for (int k = 0; k < HID; k++) a = fmaf(shf[k], W[(size_t)k * stride + j], a);
    cv[j] = a;
  }
}

// ---------- MFMA GEMM: [ROWS,128] @ [128,128] -> bf16. W fully register-resident. ----------
template <bool FP32_IN>
__global__ __launch_bounds__(256, 2) void k_gemm_mfma(const void* __restrict__ Xv,
                                                      const uint16_t* __restrict__ WP,
                                                      uint16_t* __restrict__ Y){
  const int lane = threadIdx.x & 63;
  const int wid  = threadIdx.x >> 6;
  const int gw   = blockIdx.x * 4 + wid;
  const int nw   = GEMM_BLOCKS * 4;
  const int m    = lane & 15;
  const int kq   = lane >> 4;

  FragU wf[8][4];
#pragma unroll
  for (int c = 0; c < 8; c++)
#pragma unroll
    for (int s = 0; s < 4; s++)
      wf[c][s].u = *((const ushort8*)(WP + (size_t)(((c * 4 + s) * 64 + lane) * 8)));

  for (int t = gw; t < GEMM_TILES; t += nw){
    const int row0 = t * 16;
    FragU af[4];
    if (FP32_IN){
      const float* X = (const float*)Xv;
#pragma unroll
      for (int s = 0; s < 4; s++){
        const float* p = X + (size_t)(row0 + m) * HID + s * 32 + kq * 8;
        floatx4 f0 = *((const floatx4*)p);
        floatx4 f1 = *((const floatx4*)(p + 4));
        ushort8 r;
#pragma unroll
        for (int j = 0; j < 4; j++){ r[j] = f2bf(f0[j]); r[j + 4] = f2bf(f1[j]); }
        af[s].u = r;
      }
    } else {
      const uint16_t* X = (const uint16_t*)Xv;
#pragma unroll
      for (int s = 0; s < 4; s++)
        af[s].u = *((const ushort8*)(X + (size_t)(row0 + m) * HID + s * 32 + kq * 8));
    }

    floatx4 acc[8];
#pragma unroll
    for (int c = 0; c < 8; c++) acc[c] = floatx4{0.f, 0.f, 0.f, 0.f};
#pragma unroll
    for (int s = 0; s < 4; s++)
#pragma unroll
      for (int c = 0; c < 8; c++)
        acc[c] = __builtin_amdgcn_mfma_f32_16x16x32_bf16(af[s].b, wf[c][s].b, acc[c], 0, 0, 0);

    // C/D layout: col = lane&15, row = (lane>>4)*4 + reg
#pragma unroll
    for (int c = 0; c < 8; c++)
#pragma unroll
      for (int i = 0; i < 4; i++)
        Y[(size_t)(row0 + kq * 4 + i) * HID + c * 16 + m] = f2bf(acc[c][i]);
  }
}

// ---------- MFMA classifier: out = h @ WcS + cvec (fp32 out) ----------
__global__ __launch_bounds__(256) void k_cls_mfma(const uint16_t* __restrict__ H,
                                                  const uint16_t* __restrict__ WPC,
                                                  const float* __restrict__ cvec,
                                                  float* __restrict__ out){
  const int lane = threadIdx.x & 63;
  const int wid  = threadIdx.x >> 6;
  const int gw   = blockIdx.x * 4 + wid;
  const int nw   = GEMM_BLOCKS * 4;
  const int m    = lane & 15;
  const int kq   = lane >> 4;

  FragU wf[4];
#pragma unroll
  for (int s = 0; s < 4; s++)
    wf[s].u = *((const ushort8*)(WPC + (size_t)((s * 64 + lane) * 8)));
  const float cv = cvec[m];

  for (int t = gw; t < GEMM_TILES; t += nw){
    const int row0 = t * 16;
    FragU af[4];
#pragma unroll
    for (int s = 0; s < 4; s++)
      af[s].u = *((const ushort8*)(H + (size_t)(row0 + m) * HID + s * 32 + kq * 8));
    floatx4 acc = floatx4{0.f, 0.f, 0.f, 0.f};
#pragma unroll
    for (int s = 0; s < 4; s++)
      acc = __builtin_amdgcn_mfma_f32_16x16x32_bf16(af[s].b, wf[s].b, acc, 0, 0, 0);
#pragma unroll
    for (int i = 0; i < 4; i++)
      out[(size_t)(row0 + kq * 4 + i) * OUTD + m] = acc[i] + cv;
  }
}

// ---------- aggregation + rank-1 (wsum*cvec) + bias + relu + BN partial stats ----------
__global__ __launch_bounds__(256) void k_agg(const uint16_t* __restrict__ XW,
                                             const int* __restrict__ rp,
                                             const int* __restrict__ csrc,
                                             const float* __restrict__ cw,
                                             const float* __restrict__ dinv,
                                             const float* __restrict__ bias,
                                             const float* __restrict__ cvec,
                                             uint16_t* __restrict__ H,
                                             float* __restrict__ psum,
                                             float* __restrict__ pssq){
  __shared__ float lsum[128];
  __shared__ float lssq[128];
  const int tid = threadIdx.x;
  if (tid < 128){ lsum[tid] = 0.f; lssq[tid] = 0.f; }
  __syncthreads();

  const int lane = tid & 63;
  const int wid  = tid >> 6;
  const int gw   = blockIdx.x * 4 + wid;
  const int nw   = AGG_BLOCKS * 4;
  const uint32_t* Xu = (const uint32_t*)XW;   // one row = 64 packed bf16x2
  uint32_t* Hu = (uint32_t*)H;
  const int f0 = lane * 2;
  const float b0 = bias[f0], b1 = bias[f0 + 1];
  const float c0 = cvec ? cvec[f0] : 0.f;
  const float c1 = cvec ? cvec[f0 + 1] : 0.f;
  float ts0 = 0.f, ts1 = 0.f, tq0 = 0.f, tq1 = 0.f;

  for (int node = gw; node < N_NODES; node += nw){
    const float di = dinv[node];
    const float sn = di * di;
    const int e0 = rp[node], e1 = rp[node + 1];
    uint32_t s0 = Xu[(size_t)node * 64 + lane];
    uint32_t s1 = Xu[(size_t)(N_NODES + node) * 64 + lane];
    float a0x = sn * bf_lo(s0), a0y = sn * bf_hi(s0);
    float a1x = sn * bf_lo(s1), a1y = sn * bf_hi(s1);
    float wsum = sn;
    int e = e0;
    // unroll x4: batch index loads, then 8 independent row gathers in flight
    for (; e + 4 <= e1; e += 4){
      int i0 = csrc[e],     i1 = csrc[e + 1], i2 = csrc[e + 2], i3 = csrc[e + 3];
      float w0 = cw[e],     w1 = cw[e + 1],   w2 = cw[e + 2],   w3 = cw[e + 3];
      uint32_t q00 = Xu[(size_t)i0 * 64 + lane], q01 = Xu[(size_t)(N_NODES + i0) * 64 + lane];
      uint32_t q10 = Xu[(size_t)i1 * 64 + lane], q11 = Xu[(size_t)(N_NODES + i1) * 64 + lane];
      uint32_t q20 = Xu[(size_t)i2 * 64 + lane], q21 = Xu[(size_t)(N_NODES + i2) * 64 + lane];
      uint32_t q30 = Xu[(size_t)i3 * 64 + lane], q31 = Xu[(size_t)(N_NODES + i3) * 64 + lane];
      a0x = fmaf(w0, bf_lo(q00), a0x); a0y = fmaf(w0, bf_hi(q00), a0y);
      a1x = fmaf(w0, bf_lo(q01), a1x); a1y = fmaf(w0, bf_hi(q01), a1y);
      a0x = fmaf(w1, bf_lo(q10), a0x); a0y = fmaf(w1, bf_hi(q10), a0y);
      a1x = fmaf(w1, bf_lo(q11), a1x); a1y = fmaf(w1, bf_hi(q11), a1y);
      a0x = fmaf(w2, bf_lo(q20), a0x); a0y = fmaf(w2, bf_hi(q20), a0y);
      a1x = fmaf(w2, bf_lo(q21), a1x); a1y = fmaf(w2, bf_hi(q21), a1y);
      a0x = fmaf(w3, bf_lo(q30), a0x); a0y = fmaf(w3, bf_hi(q30), a0y);
      a1x = fmaf(w3, bf_lo(q31), a1x); a1y = fmaf(w3, bf_hi(q31), a1y);
      wsum += w0 + w1 + w2 + w3;
    }
    for (; e < e1; e++){
      int src = csrc[e];
      float w = cw[e];
      uint32_t g0 = Xu[(size_t)src * 64 + lane];
      uint32_t g1 = Xu[(size_t)(N_NODES + src) * 64 + lane];
      a0x = fmaf(w, bf_lo(g0), a0x); a0y = fmaf(w, bf_hi(g0), a0y);
      a1x = fmaf(w, bf_lo(g1), a1x); a1y = fmaf(w, bf_hi(g1), a1y);
      wsum += w;
    }
    // rank-1 BN-fold term + bias + relu
    a0x = fmaxf(fmaf(wsum, c0, a0x) + b0, 0.f); a0y = fmaxf(fmaf(wsum, c1, a0y) + b1, 0.f);
    a1x = fmaxf(fmaf(wsum, c0, a1x) + b0, 0.f); a1y = fmaxf(fmaf(wsum, c1, a1y) + b1, 0.f);
    Hu[(size_t)node * 64 + lane]             = (uint32_t)f2bf(a0x) | ((uint32_t)f2bf(a0y) << 16);
    Hu[(size_t)(N_NODES + node) * 64 + lane] = (uint32_t)f2bf(a1x) | ((uint32_t)f2bf(a1y) << 16);
    ts0 += a0x + a1x; ts1 += a0y + a1y;
    tq0 += a0x * a0x + a1x * a1x; tq1 += a0y * a0y + a1y * a1y;
  }

  atomicAdd(&lsum[f0],     ts0); atomicAdd(&lsum[f0 + 1], ts1);
  atomicAdd(&lssq[f0],     tq0); atomicAdd(&lssq[f0 + 1], tq1);
  __syncthreads();
  if (tid < 128){
    psum[(size_t)blockIdx.x * 128 + tid] = lsum[tid];
    pssq[(size_t)blockIdx.x * 128 + tid] = lssq[tid];
  }
}

// ---------- BN mid-reduction: 2048 partial rows -> 32 ----------
__global__ __launch_bounds__(256) void k_bnmid(const float* __restrict__ psum,
                                               const float* __restrict__ pssq,
                                               float* __restrict__ msum,
                                               float* __restrict__ mssq){
  __shared__ float ss[2][128];
  __shared__ float sq[2][128];
  const int tid = threadIdx.x;
  const int f  = tid & 127;
  const int sl = tid >> 7;
  const int rows_per = AGG_BLOCKS / MID_BLOCKS;  // 64
  const int base = blockIdx.x * rows_per;
  float s = 0.f, q = 0.f;
  for (int r = base + sl; r < base + rows_per; r += 2){
    s += psum[(size_t)r * 128 + f];
    q += pssq[(size_t)r * 128 + f];
  }
  ss[sl][f] = s; sq[sl][f] = q;
  __syncthreads();
  if (tid < 128){
    msum[(size_t)blockIdx.x * 128 + tid] = ss[0][tid] + ss[1][tid];
    mssq[(size_t)blockIdx.x * 128 + tid] = sq[0][tid] + sq[1][tid];
  }
}

// ---------- BN finalize ----------
__global__ __launch_bounds__(128) void k_bnfin(const float* __restrict__ msum,
                                               const float* __restrict__ mssq,
                                               const float* __restrict__ gamma,
                                               const float* __restrict__ beta,
                                               float* __restrict__ sca,
                                               float* __restrict__ shf){
  const int f = threadIdx.x;
  float S = 0.f, Q = 0.f;
#pragma unroll
  for (int b = 0; b < MID_BLOCKS; b++){
    S += msum[(size_t)b * 128 + f];
    Q += mssq[(size_t)b * 128 + f];
  }
  const float inv = 1.0f / (float)ROWS;
  float mu = S * inv;
  float var = fmaxf(Q * inv - mu * mu, 0.f);
  float rstd = 1.0f / sqrtf(var + 1e-5f);
  float sc = gamma[f] * rstd;
  sca[f] = sc;
  shf[f] = fmaf(-mu, sc, beta[f]);
}

// ---------- launch ----------
extern "C" void kernel_launch(void* const* d_in, const int* in_sizes, int n_in,
                              void* d_out, int out_size, void* d_ws, size_t ws_size,
                              hipStream_t stream){
  const float* x   = (const float*)d_in[0];
  const int*   ei  = (const int*)d_in[1];
  const float* ewp = (const float*)d_in[2];
  const float* W1  = (const float*)d_in[3];
  const float* b1  = (const float*)d_in[4];
  const float* W2  = (const float*)d_in[5];
  const float* b2  = (const float*)d_in[6];
  const float* g1  = (const float*)d_in[7];
  const float* be1 = (const float*)d_in[8];
  const float* g2  = (const float*)d_in[9];
  const float* be2 = (const float*)d_in[10];
  const float* Wc  = (const float*)d_in[11];
  const float* bc  = (const float*)d_in[12];
  float* out = (float*)d_out;

  char* wsb = (char*)d_ws;
  size_t off = 0;
  auto give = [&](size_t bytes) -> void* {
    void* p = wsb + off;
    off = (off + bytes + 255) & ~(size_t)255;
    return p;
  };
  uint16_t* XW  = (uint16_t*)give((size_t)ROWS * 128 * 2);
  uint16_t* Hb  = (uint16_t*)give((size_t)ROWS * 128 * 2);
  float* EW     = (float*)give((size_t)N_EDGES * 4);
  float* DEG    = (float*)give((size_t)N_NODES * 4);   // becomes dinv in-place
  int*   CSRC   = (int*)give((size_t)N_EDGES * 4);
  float* CW     = (float*)give((size_t)N_EDGES * 4);
  int*   COUNTS = (int*)give((size_t)N_NODES * 4);
  int*   RP     = (int*)give((size_t)(N_NODES + 1) * 4);
  int*   CUR    = (int*)give((size_t)N_NODES * 4);
  int*   BSUM   = (int*)give(1024);
  float* PSUM   = (float*)give((size_t)AGG_BLOCKS * 128 * 4);
  float* PSSQ   = (float*)give((size_t)AGG_BLOCKS * 128 * 4);
  float* MSUM   = (float*)give((size_t)MID_BLOCKS * 128 * 4);
  float* MSSQ   = (float*)give((size_t)MID_BLOCKS * 128 * 4);
  float* SCA1   = (float*)give(512);
  float* SHF1   = (float*)give(512);
  float* SCA2   = (float*)give(512);
  float* SHF2   = (float*)give(512);
  uint16_t* WP1 = (uint16_t*)give((size_t)HID * HID * 2);
  uint16_t* WP2 = (uint16_t*)give((size_t)HID * HID * 2);
  uint16_t* WPC = (uint16_t*)give((size_t)HID * OUTD * 2);
  float* C2     = (float*)give(512);
  float* CVC    = (float*)give(64);
  (void)ws_size; (void)n_in; (void)in_sizes; (void)out_size;

  const int nb_nodes = (N_NODES + 255) / 256;   // 196
  const int nb_edges = (N_EDGES + 255) / 256;   // 2500

  k_init<<<nb_nodes, 256, 0, stream>>>(DEG, COUNTS);
  k_edge1<<<nb_edges, 256, 0, stream>>>(ei, ewp, EW, DEG, COUNTS);
  k_scan_bsum<<<SCAN_BLOCKS, 256, 0, stream>>>(COUNTS, BSUM, DEG);
  k_scan_excl<<<1, 256, 0, stream>>>(BSUM);
  k_scan_write<<<SCAN_BLOCKS, 256, 0, stream>>>(COUNTS, BSUM, RP, CUR);
  k_fill<<<nb_edges, 256, 0, stream>>>(ei, EW, DEG, CUR, CSRC, CW);
  k_wpack<<<8, 256, 0, stream>>>(W1, nullptr, WP1);

  // layer 1: xw1 = bf16(x) @ W1
  k_gemm_mfma<true><<<GEMM_BLOCKS, 256, 0, stream>>>(x, WP1, XW);
  k_agg<<<AGG_BLOCKS, 256, 0, stream>>>(XW, RP, CSRC, CW, DEG, b1, nullptr, Hb, PSUM, PSSQ);
  k_bnmid<<<MID_BLOCKS, 256, 0, stream>>>(PSUM, PSSQ, MSUM, MSSQ);
  k_bnfin<<<1, 128, 0, stream>>>(MSUM, MSSQ, g1, be1, SCA1, SHF1);

  // layer 2: bn1 folded -> W2' = s1 (.) W2, c2 = t1 @ W2 (applied via wsum in agg)
  k_wpack<<<8, 256, 0, stream>>>(W2, SCA1, WP2);
  k_cvec<<<1, 128, 0, stream>>>(SHF1, W2, nullptr, C2, HID, HID);
  k_gemm_mfma<false><<<GEMM_BLOCKS, 256, 0, stream>>>(Hb, WP2, XW);
  k_agg<<<AGG_BLOCKS, 256, 0, stream>>>(XW, RP, CSRC, CW, DEG, b2, C2, Hb, PSUM, PSSQ);
  k_bnmid<<<MID_BLOCKS, 256, 0, stream>>>(PSUM, PSSQ, MSUM, MSSQ);
  k_bnfin<<<1, 128, 0, stream>>>(MSUM, MSSQ, g2, be2, SCA2, SHF2);

  // classifier: bn2 folded -> WcS = s2 (.) Wc, cvec = t2 @ Wc + bc
  k_wpackc<<<1, 256, 0, stream>>>(Wc, SCA2, WPC);
  k_cvec<<<1, 128, 0, stream>>>(SHF2, Wc, bc, CVC, OUTD, OUTD);
  k_cls_mfma<<<GEMM_BLOCKS, 256, 0, stream>>>(Hb, WPC, CVC, out);
}

// Round 4
// 380.416 us; speedup vs baseline: 1.7923x; 1.0507x over previous
//
#include <hip/hip_runtime.h>
#include <hip/hip_bf16.h>
#include <cstdint>
#include <cstddef>

#define N_NODES 50000
#define N_EDGES 640000
#define ROWS    100000   // B * N_NODES
#define HID     128
#define OUTD    16
#define AGG_BLOCKS 2048
#define MID_BLOCKS 32
#define SCAN_BLOCKS 196  // ceil(50000/256)
#define GEMM_BLOCKS 512
#define GEMM_TILES  (ROWS / 16)   // 6250

// ---------- types ----------
typedef __attribute__((ext_vector_type(8))) uint16_t ushort8;
typedef __attribute__((ext_vector_type(8))) __bf16   bf16x8;
typedef __attribute__((ext_vector_type(4))) float    floatx4;

union FragU { ushort8 u; bf16x8 b; };

// ---------- bf16 helpers ----------
__device__ __forceinline__ float bf_lo(uint32_t u){
  union { uint32_t u; float f; } c; c.u = u << 16; return c.f;
}
__device__ __forceinline__ float bf_hi(uint32_t u){
  union { uint32_t u; float f; } c; c.u = u & 0xffff0000u; return c.f;
}
__device__ __forceinline__ uint16_t f2bf(float f){
  union { float f; uint32_t u; } c; c.f = f;
  uint32_t u = c.u;
  uint32_t r = (u + 0x7fffu + ((u >> 16) & 1u)) >> 16;  // RNE
  return (uint16_t)r;
}

// ---------- edge prep ----------
// DC[i]: packed u64 accumulator — bits[63:44] = in-degree count, bits[43:0] = sum(w) in 2^20 fixed point.
// Single device-scope atomic per edge (vs 2): halves the ~32B/atomic fabric write traffic.
__global__ void k_init(unsigned long long* __restrict__ dc){
  int i = blockIdx.x * 256 + threadIdx.x;
  if (i < N_NODES) dc[i] = 0ull;
}

__global__ void k_edge1(const int* __restrict__ ei, const float* __restrict__ ewp,
                        unsigned long long* __restrict__ dc){
  int e = blockIdx.x * 256 + threadIdx.x;
  if (e < N_EDGES){
    float w = expf(ewp[e]);
    int c = ei[N_EDGES + e];
    unsigned long long inc = (1ull << 44) | (unsigned long long)(w * 1048576.0f + 0.5f);
    atomicAdd(&dc[c], inc);
  }
}

// unpack DC -> dinv (self-loop weight 1 added here), block-sum counts for scan
__global__ void k_scan_bsum(const unsigned long long* __restrict__ dc, int* __restrict__ bsum,
                            float* __restrict__ dinv){
  __shared__ int sd[256];
  int tid = threadIdx.x;
  int i = blockIdx.x * 256 + tid;
  int cnt = 0;
  if (i < N_NODES){
    unsigned long long v = dc[i];
    cnt = (int)(v >> 44);
    float deg = 1.0f + (float)((double)(v & ((1ull << 44) - 1)) * (1.0 / 1048576.0));
    dinv[i] = 1.0f / sqrtf(deg);
  }
  sd[tid] = cnt;
  __syncthreads();
  for (int off = 128; off > 0; off >>= 1){
    if (tid < off) sd[tid] += sd[tid + off];
    __syncthreads();
  }
  if (tid == 0) bsum[blockIdx.x] = sd[0];
}

__global__ void k_scan_excl(int* __restrict__ bsum){
  __shared__ int sd[256];
  int tid = threadIdx.x;
  sd[tid] = (tid < SCAN_BLOCKS) ? bsum[tid] : 0;
  __syncthreads();
  if (tid == 0){
    int run = 0;
    for (int i = 0; i < SCAN_BLOCKS; i++){ int t = sd[i]; sd[i] = run; run += t; }
  }
  __syncthreads();
  if (tid < SCAN_BLOCKS) bsum[tid] = sd[tid];
}

__global__ void k_scan_write(const unsigned long long* __restrict__ dc, const int* __restrict__ bsum,
                             int* __restrict__ rp, int* __restrict__ cur){
  __shared__ int sd[256];
  int tid = threadIdx.x;
  int i = blockIdx.x * 256 + tid;
  int v = (i < N_NODES) ? (int)(dc[i] >> 44) : 0;
  sd[tid] = v;
  __syncthreads();
  for (int off = 1; off < 256; off <<= 1){
    int t = (tid >= off) ? sd[tid - off] : 0;
    __syncthreads();
    sd[tid] += t;
    __syncthreads();
  }
  if (i < N_NODES){
    int r = bsum[blockIdx.x] + sd[tid] - v;
    rp[i] = r;
    cur[i] = r;
  }
  if (blockIdx.x == 0 && tid == 0) rp[N_NODES] = N_EDGES;
}

// fill CSR with packed record (norm<<32 | src): one 8B scattered store per edge
__global__ void k_fill(const int* __restrict__ ei, const float* __restrict__ ewp,
                       const float* __restrict__ dinv, int* __restrict__ cur,
                       unsigned long long* __restrict__ edg){
  int e = blockIdx.x * 256 + threadIdx.x;
  if (e < N_EDGES){
    int r = ei[e];
    int c = ei[N_EDGES + e];
    float w = expf(ewp[e]);
    float nrm = dinv[r] * w * dinv[c];
    int p = atomicAdd(&cur[c], 1);
    edg[p] = ((unsigned long long)__float_as_uint(nrm) << 32) | (unsigned int)r;
  }
}

// ---------- weight packing into MFMA B-fragment layout ----------
// B-frag for 16x16x32: lane L holds col n=L&15, k = (L>>4)*8 + j (j=0..7 contiguous)
__global__ void k_wpack(const float* __restrict__ W, const float* __restrict__ sca,
                        uint16_t* __restrict__ WP){
  int t = blockIdx.x * 256 + threadIdx.x;  // 0..2047 (8 blocks)
  int L = t & 63;
  int s = (t >> 6) & 3;
  int c = t >> 8;
  int n = c * 16 + (L & 15);
  int k0 = s * 32 + (L >> 4) * 8;
  ushort8 r;
#pragma unroll
  for (int j = 0; j < 8; j++){
    float w = W[(size_t)(k0 + j) * HID + n];
    if (sca) w *= sca[k0 + j];
    r[j] = f2bf(w);
  }
  *((ushort8*)(WP + (size_t)t * 8)) = r;
}

__global__ void k_wpackc(const float* __restrict__ Wc, const float* __restrict__ sca,
                         uint16_t* __restrict__ WPC){
  int t = threadIdx.x;          // 256
  int L = t & 63;
  int s = t >> 6;
  int n = L & 15;
  int k0 = s * 32 + (L >> 4) * 8;
  ushort8 r;
#pragma unroll
  for (int j = 0; j < 8; j++)
    r[j] = f2bf(sca[k0 + j] * Wc[(size_t)(k0 + j) * OUTD + n]);
  *((ushort8*)(WPC + (size_t)t * 8)) = r;
}

// cv[j] = sum_k shf[k]*W[k*stride+j] (+ bias[j])
__global__ void k_cvec(const float* __restrict__ shf, const float* __restrict__ W,
                       const float* __restrict__ bias, float* __restrict__ cv, int ncol, int stride){
  int j = threadIdx.x;
  if (j < ncol){
    float a = bias ? bias[j] : 0.f;
    for (int k = 0; k < HID; k++) a = fmaf(shf[k], W[(size_t)k * stride + j], a);
    cv[j] = a;
  }
}

// ---------- MFMA GEMM: [ROWS,128] @ [128,128] -> bf16. W fully register-resident. ----------
template <bool FP32_IN>
__global__ __launch_bounds__(256, 2) void k_gemm_mfma(const void* __restrict__ Xv,
                                                      const uint16_t* __restrict__ WP,
                                                      uint16_t* __restrict__ Y){
  const int lane = threadIdx.x & 63;
  const int wid  = threadIdx.x >> 6;
  const int gw   = blockIdx.x * 4 + wid;
  const int nw   = GEMM_BLOCKS * 4;
  const int m    = lane & 15;
  const int kq   = lane >> 4;

  FragU wf[8][4];
#pragma unroll
  for (int c = 0; c < 8; c++)
#pragma unroll
    for (int s = 0; s < 4; s++)
      wf[c][s].u = *((const ushort8*)(WP + (size_t)(((c * 4 + s) * 64 + lane) * 8)));

  for (int t = gw; t < GEMM_TILES; t += nw){
    const int row0 = t * 16;
    FragU af[4];
    if (FP32_IN){
      const float* X = (const float*)Xv;
#pragma unroll
      for (int s = 0; s < 4; s++){
        const float* p = X + (size_t)(row0 + m) * HID + s * 32 + kq * 8;
        floatx4 f0 = *((const floatx4*)p);
        floatx4 f1 = *((const floatx4*)(p + 4));
        ushort8 r;
#pragma unroll
        for (int j = 0; j < 4; j++){ r[j] = f2bf(f0[j]); r[j + 4] = f2bf(f1[j]); }
        af[s].u = r;
      }
    } else {
      const uint16_t* X = (const uint16_t*)Xv;
#pragma unroll
      for (int s = 0; s < 4; s++)
        af[s].u = *((const ushort8*)(X + (size_t)(row0 + m) * HID + s * 32 + kq * 8));
    }

    floatx4 acc[8];
#pragma unroll
    for (int c = 0; c < 8; c++) acc[c] = floatx4{0.f, 0.f, 0.f, 0.f};
#pragma unroll
    for (int s = 0; s < 4; s++)
#pragma unroll
      for (int c = 0; c < 8; c++)
        acc[c] = __builtin_amdgcn_mfma_f32_16x16x32_bf16(af[s].b, wf[c][s].b, acc[c], 0, 0, 0);

    // C/D layout: col = lane&15, row = (lane>>4)*4 + reg
#pragma unroll
    for (int c = 0; c < 8; c++)
#pragma unroll
      for (int i = 0; i < 4; i++)
        Y[(size_t)(row0 + kq * 4 + i) * HID + c * 16 + m] = f2bf(acc[c][i]);
  }
}

// ---------- MFMA classifier: out = h @ WcS + cvec (fp32 out) ----------
__global__ __launch_bounds__(256) void k_cls_mfma(const uint16_t* __restrict__ H,
                                                  const uint16_t* __restrict__ WPC,
                                                  const float* __restrict__ cvec,
                                                  float* __restrict__ out){
  const int lane = threadIdx.x & 63;
  const int wid  = threadIdx.x >> 6;
  const int gw   = blockIdx.x * 4 + wid;
  const int nw   = GEMM_BLOCKS * 4;
  const int m    = lane & 15;
  const int kq   = lane >> 4;

  FragU wf[4];
#pragma unroll
  for (int s = 0; s < 4; s++)
    wf[s].u = *((const ushort8*)(WPC + (size_t)((s * 64 + lane) * 8)));
  const float cv = cvec[m];

  for (int t = gw; t < GEMM_TILES; t += nw){
    const int row0 = t * 16;
    FragU af[4];
#pragma unroll
    for (int s = 0; s < 4; s++)
      af[s].u = *((const ushort8*)(H + (size_t)(row0 + m) * HID + s * 32 + kq * 8));
    floatx4 acc = floatx4{0.f, 0.f, 0.f, 0.f};
#pragma unroll
    for (int s = 0; s < 4; s++)
      acc = __builtin_amdgcn_mfma_f32_16x16x32_bf16(af[s].b, wf[s].b, acc, 0, 0, 0);
#pragma unroll
    for (int i = 0; i < 4; i++)
      out[(size_t)(row0 + kq * 4 + i) * OUTD + m] = acc[i] + cv;
  }
}

// ---------- aggregation + rank-1 (wsum*cvec) + bias + relu + BN partial stats ----------
__global__ __launch_bounds__(256) void k_agg(const uint16_t* __restrict__ XW,
                                             const int* __restrict__ rp,
                                             const unsigned long long* __restrict__ edg,
                                             const float* __restrict__ dinv,
                                             const float* __restrict__ bias,
                                             const float* __restrict__ cvec,
                                             uint16_t* __restrict__ H,
                                             float* __restrict__ psum,
                                             float* __restrict__ pssq){
  __shared__ float lsum[128];
  __shared__ float lssq[128];
  const int tid = threadIdx.x;
  if (tid < 128){ lsum[tid] = 0.f; lssq[tid] = 0.f; }
  __syncthreads();

  const int lane = tid & 63;
  const int wid  = tid >> 6;
  const int gw   = blockIdx.x * 4 + wid;
  const int nw   = AGG_BLOCKS * 4;
  const uint32_t* Xu = (const uint32_t*)XW;   // one row = 64 packed bf16x2
  uint32_t* Hu = (uint32_t*)H;
  const int f0 = lane * 2;
  const float b0 = bias[f0], b1 = bias[f0 + 1];
  const float c0 = cvec ? cvec[f0] : 0.f;
  const float c1 = cvec ? cvec[f0 + 1] : 0.f;
  float ts0 = 0.f, ts1 = 0.f, tq0 = 0.f, tq1 = 0.f;

  for (int node = gw; node < N_NODES; node += nw){
    const float di = dinv[node];
    const float sn = di * di;
    const int e0 = rp[node], e1 = rp[node + 1];
    uint32_t s0 = Xu[(size_t)node * 64 + lane];
    uint32_t s1 = Xu[(size_t)(N_NODES + node) * 64 + lane];
    float a0x = sn * bf_lo(s0), a0y = sn * bf_hi(s0);
    float a1x = sn * bf_lo(s1), a1y = sn * bf_hi(s1);
    float wsum = sn;
    int e = e0;
    // unroll x8: 8 packed edge recs, then 16 independent row gathers in flight
    for (; e + 8 <= e1; e += 8){
      unsigned long long rec[8];
#pragma unroll
      for (int u = 0; u < 8; u++) rec[u] = edg[e + u];
      uint32_t q0[8], q1[8];
#pragma unroll
      for (int u = 0; u < 8; u++){
        size_t src = (uint32_t)rec[u];
        q0[u] = Xu[src * 64 + lane];
        q1[u] = Xu[(N_NODES + src) * 64 + lane];
      }
#pragma unroll
      for (int u = 0; u < 8; u++){
        float w = __uint_as_float((uint32_t)(rec[u] >> 32));
        a0x = fmaf(w, bf_lo(q0[u]), a0x); a0y = fmaf(w, bf_hi(q0[u]), a0y);
        a1x = fmaf(w, bf_lo(q1[u]), a1x); a1y = fmaf(w, bf_hi(q1[u]), a1y);
        wsum += w;
      }
    }
    for (; e + 4 <= e1; e += 4){
      unsigned long long rec[4];
#pragma unroll
      for (int u = 0; u < 4; u++) rec[u] = edg[e + u];
      uint32_t q0[4], q1[4];
#pragma unroll
      for (int u = 0; u < 4; u++){
        size_t src = (uint32_t)rec[u];
        q0[u] = Xu[src * 64 + lane];
        q1[u] = Xu[(N_NODES + src) * 64 + lane];
      }
#pragma unroll
      for (int u = 0; u < 4; u++){
        float w = __uint_as_float((uint32_t)(rec[u] >> 32));
        a0x = fmaf(w, bf_lo(q0[u]), a0x); a0y = fmaf(w, bf_hi(q0[u]), a0y);
        a1x = fmaf(w, bf_lo(q1[u]), a1x); a1y = fmaf(w, bf_hi(q1[u]), a1y);
        wsum += w;
      }
    }
    for (; e < e1; e++){
      unsigned long long rec = edg[e];
      size_t src = (uint32_t)rec;
      float w = __uint_as_float((uint32_t)(rec >> 32));
      uint32_t g0 = Xu[src * 64 + lane];
      uint32_t g1 = Xu[(N_NODES + src) * 64 + lane];
      a0x = fmaf(w, bf_lo(g0), a0x); a0y = fmaf(w, bf_hi(g0), a0y);
      a1x = fmaf(w, bf_lo(g1), a1x); a1y = fmaf(w, bf_hi(g1), a1y);
      wsum += w;
    }
    // rank-1 BN-fold term + bias + relu
    a0x = fmaxf(fmaf(wsum, c0, a0x) + b0, 0.f); a0y = fmaxf(fmaf(wsum, c1, a0y) + b1, 0.f);
    a1x = fmaxf(fmaf(wsum, c0, a1x) + b0, 0.f); a1y = fmaxf(fmaf(wsum, c1, a1y) + b1, 0.f);
    Hu[(size_t)node * 64 + lane]             = (uint32_t)f2bf(a0x) | ((uint32_t)f2bf(a0y) << 16);
    Hu[(size_t)(N_NODES + node) * 64 + lane] = (uint32_t)f2bf(a1x) | ((uint32_t)f2bf(a1y) << 16);
    ts0 += a0x + a1x; ts1 += a0y + a1y;
    tq0 += a0x * a0x + a1x * a1x; tq1 += a0y * a0y + a1y * a1y;
  }

  atomicAdd(&lsum[f0],     ts0); atomicAdd(&lsum[f0 + 1], ts1);
  atomicAdd(&lssq[f0],     tq0); atomicAdd(&lssq[f0 + 1], tq1);
  __syncthreads();
  if (tid < 128){
    psum[(size_t)blockIdx.x * 128 + tid] = lsum[tid];
    pssq[(size_t)blockIdx.x * 128 + tid] = lssq[tid];
  }
}

// ---------- BN mid-reduction: 2048 partial rows -> 32 ----------
__global__ __launch_bounds__(256) void k_bnmid(const float* __restrict__ psum,
                                               const float* __restrict__ pssq,
                                               float* __restrict__ msum,
                                               float* __restrict__ mssq){
  __shared__ float ss[2][128];
  __shared__ float sq[2][128];
  const int tid = threadIdx.x;
  const int f  = tid & 127;
  const int sl = tid >> 7;
  const int rows_per = AGG_BLOCKS / MID_BLOCKS;  // 64
  const int base = blockIdx.x * rows_per;
  float s = 0.f, q = 0.f;
  for (int r = base + sl; r < base + rows_per; r += 2){
    s += psum[(size_t)r * 128 + f];
    q += pssq[(size_t)r * 128 + f];
  }
  ss[sl][f] = s; sq[sl][f] = q;
  __syncthreads();
  if (tid < 128){
    msum[(size_t)blockIdx.x * 128 + tid] = ss[0][tid] + ss[1][tid];
    mssq[(size_t)blockIdx.x * 128 + tid] = sq[0][tid] + sq[1][tid];
  }
}

// ---------- BN finalize ----------
__global__ __launch_bounds__(128) void k_bnfin(const float* __restrict__ msum,
                                               const float* __restrict__ mssq,
                                               const float* __restrict__ gamma,
                                               const float* __restrict__ beta,
                                               float* __restrict__ sca,
                                               float* __restrict__ shf){
  const int f = threadIdx.x;
  float S = 0.f, Q = 0.f;
#pragma unroll
  for (int b = 0; b < MID_BLOCKS; b++){
    S += msum[(size_t)b * 128 + f];
    Q += mssq[(size_t)b * 128 + f];
  }
  const float inv = 1.0f / (float)ROWS;
  float mu = S * inv;
  float var = fmaxf(Q * inv - mu * mu, 0.f);
  float rstd = 1.0f / sqrtf(var + 1e-5f);
  float sc = gamma[f] * rstd;
  sca[f] = sc;
  shf[f] = fmaf(-mu, sc, beta[f]);
}

// ---------- launch ----------
extern "C" void kernel_launch(void* const* d_in, const int* in_sizes, int n_in,
                              void* d_out, int out_size, void* d_ws, size_t ws_size,
                              hipStream_t stream){
  const float* x   = (const float*)d_in[0];
  const int*   ei  = (const int*)d_in[1];
  const float* ewp = (const float*)d_in[2];
  const float* W1  = (const float*)d_in[3];
  const float* b1  = (const float*)d_in[4];
  const float* W2  = (const float*)d_in[5];
  const float* b2  = (const float*)d_in[6];
  const float* g1  = (const float*)d_in[7];
  const float* be1 = (const float*)d_in[8];
  const float* g2  = (const float*)d_in[9];
  const float* be2 = (const float*)d_in[10];
  const float* Wc  = (const float*)d_in[11];
  const float* bc  = (const float*)d_in[12];
  float* out = (float*)d_out;

  char* wsb = (char*)d_ws;
  size_t off = 0;
  auto give = [&](size_t bytes) -> void* {
    void* p = wsb + off;
    off = (off + bytes + 255) & ~(size_t)255;
    return p;
  };
  uint16_t* XW  = (uint16_t*)give((size_t)ROWS * 128 * 2);
  uint16_t* Hb  = (uint16_t*)give((size_t)ROWS * 128 * 2);
  unsigned long long* DC  = (unsigned long long*)give((size_t)N_NODES * 8);
  unsigned long long* EDG = (unsigned long long*)give((size_t)N_EDGES * 8);
  float* DINV   = (float*)give((size_t)N_NODES * 4);
  int*   RP     = (int*)give((size_t)(N_NODES + 1) * 4);
  int*   CUR    = (int*)give((size_t)N_NODES * 4);
  int*   BSUM   = (int*)give(1024);
  float* PSUM   = (float*)give((size_t)AGG_BLOCKS * 128 * 4);
  float* PSSQ   = (float*)give((size_t)AGG_BLOCKS * 128 * 4);
  float* MSUM   = (float*)give((size_t)MID_BLOCKS * 128 * 4);
  float* MSSQ   = (float*)give((size_t)MID_BLOCKS * 128 * 4);
  float* SCA1   = (float*)give(512);
  float* SHF1   = (float*)give(512);
  float* SCA2   = (float*)give(512);
  float* SHF2   = (float*)give(512);
  uint16_t* WP1 = (uint16_t*)give((size_t)HID * HID * 2);
  uint16_t* WP2 = (uint16_t*)give((size_t)HID * HID * 2);
  uint16_t* WPC = (uint16_t*)give((size_t)HID * OUTD * 2);
  float* C2     = (float*)give(512);
  float* CVC    = (float*)give(64);
  (void)ws_size; (void)n_in; (void)in_sizes; (void)out_size;

  const int nb_nodes = (N_NODES + 255) / 256;   // 196
  const int nb_edges = (N_EDGES + 255) / 256;   // 2500

  k_init<<<nb_nodes, 256, 0, stream>>>(DC);
  k_edge1<<<nb_edges, 256, 0, stream>>>(ei, ewp, DC);
  k_scan_bsum<<<SCAN_BLOCKS, 256, 0, stream>>>(DC, BSUM, DINV);
  k_scan_excl<<<1, 256, 0, stream>>>(BSUM);
  k_scan_write<<<SCAN_BLOCKS, 256, 0, stream>>>(DC, BSUM, RP, CUR);
  k_fill<<<nb_edges, 256, 0, stream>>>(ei, ewp, DINV, CUR, EDG);
  k_wpack<<<8, 256, 0, stream>>>(W1, nullptr, WP1);

  // layer 1: xw1 = bf16(x) @ W1
  k_gemm_mfma<true><<<GEMM_BLOCKS, 256, 0, stream>>>(x, WP1, XW);
  k_agg<<<AGG_BLOCKS, 256, 0, stream>>>(XW, RP, EDG, DINV, b1, nullptr, Hb, PSUM, PSSQ);
  k_bnmid<<<MID_BLOCKS, 256, 0, stream>>>(PSUM, PSSQ, MSUM, MSSQ);
  k_bnfin<<<1, 128, 0, stream>>>(MSUM, MSSQ, g1, be1, SCA1, SHF1);

  // layer 2: bn1 folded -> W2' = s1 (.) W2, c2 = t1 @ W2 (applied via wsum in agg)
  k_wpack<<<8, 256, 0, stream>>>(W2, SCA1, WP2);
  k_cvec<<<1, 128, 0, stream>>>(SHF1, W2, nullptr, C2, HID, HID);
  k_gemm_mfma<false><<<GEMM_BLOCKS, 256, 0, stream>>>(Hb, WP2, XW);
  k_agg<<<AGG_BLOCKS, 256, 0, stream>>>(XW, RP, EDG, DINV, b2, C2, Hb, PSUM, PSSQ);
  k_bnmid<<<MID_BLOCKS, 256, 0, stream>>>(PSUM, PSSQ, MSUM, MSSQ);
  k_bnfin<<<1, 128, 0, stream>>>(MSUM, MSSQ, g2, be2, SCA2, SHF2);

  // classifier: bn2 folded -> WcS = s2 (.) Wc, cvec = t2 @ Wc + bc
  k_wpackc<<<1, 256, 0, stream>>>(Wc, SCA2, WPC);
  k_cvec<<<1, 128, 0, stream>>>(SHF2, Wc, bc, CVC, OUTD, OUTD);
  k_cls_mfma<<<GEMM_BLOCKS, 256, 0, stream>>>(Hb, WPC, CVC, out);
}

// Round 5
// 378.908 us; speedup vs baseline: 1.7995x; 1.0040x over previous
//
#include <hip/hip_runtime.h>
#include <hip/hip_bf16.h>
#include <cstdint>
#include <cstddef>

#define N_NODES 50000
#define N_EDGES 640000
#define ROWS    100000   // B * N_NODES
#define HID     128
#define OUTD    16
#define AGG_BLOCKS 2048
#define MID_BLOCKS 32
#define SCAN_BLOCKS 196  // ceil(50000/256)
#define GEMM_BLOCKS 512
#define GEMM_TILES  (N_NODES / 8)   // 6250 tiles of 8 nodes x 2 batches
#define CLS_TILES   (ROWS / 16)     // 6250

// ---------- types ----------
typedef __attribute__((ext_vector_type(8))) uint16_t ushort8;
typedef __attribute__((ext_vector_type(8))) __bf16   bf16x8;
typedef __attribute__((ext_vector_type(4))) float    floatx4;

union FragU { ushort8 u; bf16x8 b; };

// ---------- bf16 helpers ----------
__device__ __forceinline__ float bf_lo(uint32_t u){
  union { uint32_t u; float f; } c; c.u = u << 16; return c.f;
}
__device__ __forceinline__ float bf_hi(uint32_t u){
  union { uint32_t u; float f; } c; c.u = u & 0xffff0000u; return c.f;
}
__device__ __forceinline__ uint16_t f2bf(float f){
  union { float f; uint32_t u; } c; c.f = f;
  uint32_t u = c.u;
  uint32_t r = (u + 0x7fffu + ((u >> 16) & 1u)) >> 16;  // RNE
  return (uint16_t)r;
}

// XW layout (batch-pair interleaved): u32 slot [node*128 + pair*2 + b] holds
// bf16 feats {2*pair, 2*pair+1} of batch b for `node`. One node = 512 B block.
// -> k_agg fetches BOTH batches' feature pair with a single dwordx2 per lane.

// ---------- edge prep ----------
// DC[i]: bits[63:44] = in-degree count, bits[43:0] = sum(w) in 2^20 fixed point.
__global__ void k_init(unsigned long long* __restrict__ dc){
  int i = blockIdx.x * 256 + threadIdx.x;
  if (i < N_NODES) dc[i] = 0ull;
}

// single u64 atomic per edge; old count == this edge's CSR slot (saved for k_fill)
__global__ void k_edge1(const int* __restrict__ ei, const float* __restrict__ ewp,
                        unsigned long long* __restrict__ dc, unsigned int* __restrict__ slot){
  int e = blockIdx.x * 256 + threadIdx.x;
  if (e < N_EDGES){
    float w = expf(ewp[e]);
    int c = ei[N_EDGES + e];
    unsigned long long inc = (1ull << 44) | (unsigned long long)(w * 1048576.0f + 0.5f);
    unsigned long long old = atomicAdd(&dc[c], inc);
    slot[e] = (unsigned int)(old >> 44);
  }
}

// unpack DC -> dinv (self-loop weight 1 added here), block-sum counts for scan
__global__ void k_scan_bsum(const unsigned long long* __restrict__ dc, int* __restrict__ bsum,
                            float* __restrict__ dinv){
  __shared__ int sd[256];
  int tid = threadIdx.x;
  int i = blockIdx.x * 256 + tid;
  int cnt = 0;
  if (i < N_NODES){
    unsigned long long v = dc[i];
    cnt = (int)(v >> 44);
    float deg = 1.0f + (float)((double)(v & ((1ull << 44) - 1)) * (1.0 / 1048576.0));
    dinv[i] = 1.0f / sqrtf(deg);
  }
  sd[tid] = cnt;
  __syncthreads();
  for (int off = 128; off > 0; off >>= 1){
    if (tid < off) sd[tid] += sd[tid + off];
    __syncthreads();
  }
  if (tid == 0) bsum[blockIdx.x] = sd[0];
}

__global__ void k_scan_excl(int* __restrict__ bsum){
  __shared__ int sd[256];
  int tid = threadIdx.x;
  sd[tid] = (tid < SCAN_BLOCKS) ? bsum[tid] : 0;
  __syncthreads();
  if (tid == 0){
    int run = 0;
    for (int i = 0; i < SCAN_BLOCKS; i++){ int t = sd[i]; sd[i] = run; run += t; }
  }
  __syncthreads();
  if (tid < SCAN_BLOCKS) bsum[tid] = sd[tid];
}

__global__ void k_scan_write(const unsigned long long* __restrict__ dc, const int* __restrict__ bsum,
                             int* __restrict__ rp){
  __shared__ int sd[256];
  int tid = threadIdx.x;
  int i = blockIdx.x * 256 + tid;
  int v = (i < N_NODES) ? (int)(dc[i] >> 44) : 0;
  sd[tid] = v;
  __syncthreads();
  for (int off = 1; off < 256; off <<= 1){
    int t = (tid >= off) ? sd[tid - off] : 0;
    __syncthreads();
    sd[tid] += t;
    __syncthreads();
  }
  if (i < N_NODES) rp[i] = bsum[blockIdx.x] + sd[tid] - v;
  if (blockIdx.x == 0 && tid == 0) rp[N_NODES] = N_EDGES;
}

// fill CSR with packed record (norm<<32 | src); slot known -> NO atomic
__global__ void k_fill(const int* __restrict__ ei, const float* __restrict__ ewp,
                       const float* __restrict__ dinv, const unsigned int* __restrict__ slot,
                       const int* __restrict__ rp, unsigned long long* __restrict__ edg){
  int e = blockIdx.x * 256 + threadIdx.x;
  if (e < N_EDGES){
    int r = ei[e];
    int c = ei[N_EDGES + e];
    float w = expf(ewp[e]);
    float nrm = dinv[r] * w * dinv[c];
    int p = rp[c] + (int)slot[e];
    edg[p] = ((unsigned long long)__float_as_uint(nrm) << 32) | (unsigned int)r;
  }
}

// ---------- weight packing into MFMA B-fragment layout ----------
// B-frag for 16x16x32: lane L holds col n=L&15, k = (L>>4)*8 + j (j=0..7 contiguous)
__global__ void k_wpack(const float* __restrict__ W, const float* __restrict__ sca,
                        uint16_t* __restrict__ WP){
  int t = blockIdx.x * 256 + threadIdx.x;  // 0..2047 (8 blocks)
  int L = t & 63;
  int s = (t >> 6) & 3;
  int c = t >> 8;
  int n = c * 16 + (L & 15);
  int k0 = s * 32 + (L >> 4) * 8;
  ushort8 r;
#pragma unroll
  for (int j = 0; j < 8; j++){
    float w = W[(size_t)(k0 + j) * HID + n];
    if (sca) w *= sca[k0 + j];
    r[j] = f2bf(w);
  }
  *((ushort8*)(WP + (size_t)t * 8)) = r;
}

__global__ void k_wpackc(const float* __restrict__ Wc, const float* __restrict__ sca,
                         uint16_t* __restrict__ WPC){
  int t = threadIdx.x;          // 256
  int L = t & 63;
  int s = t >> 6;
  int n = L & 15;
  int k0 = s * 32 + (L >> 4) * 8;
  ushort8 r;
#pragma unroll
  for (int j = 0; j < 8; j++)
    r[j] = f2bf(sca[k0 + j] * Wc[(size_t)(k0 + j) * OUTD + n]);
  *((ushort8*)(WPC + (size_t)t * 8)) = r;
}

// cv[j] = sum_k shf[k]*W[k*stride+j] (+ bias[j])
__global__ void k_cvec(const float* __restrict__ shf, const float* __restrict__ W,
                       const float* __restrict__ bias, float* __restrict__ cv, int ncol, int stride){
  int j = threadIdx.x;
  if (j < ncol){
    float a = bias ? bias[j] : 0.f;
    for (int k = 0; k < HID; k++) a = fmaf(shf[k], W[(size_t)k * stride + j], a);
    cv[j] = a;
  }
}

// ---------- MFMA GEMM -> XW (pair-interleaved). Tile = 8 nodes x 2 batches. ----------
template <bool FP32_IN>
__global__ __launch_bounds__(256, 2) void k_gemm_mfma(const void* __restrict__ Xv,
                                                      const uint16_t* __restrict__ WP,
                                                      uint16_t* __restrict__ Y){
  const int lane = threadIdx.x & 63;
  const int wid  = threadIdx.x >> 6;
  const int gw   = blockIdx.x * 4 + wid;
  const int nw   = GEMM_BLOCKS * 4;
  const int m    = lane & 15;
  const int kq   = lane >> 4;

  FragU wf[8][4];
#pragma unroll
  for (int c = 0; c < 8; c++)
#pragma unroll
    for (int s = 0; s < 4; s++)
      wf[c][s].u = *((const ushort8*)(WP + (size_t)(((c * 4 + s) * 64 + lane) * 8)));

  for (int t = gw; t < GEMM_TILES; t += nw){
    const int n0 = t * 8;
    // A-row m -> node n0+(m>>1), batch m&1 (global row b*N+node)
    const size_t ga = (size_t)((m & 1) * N_NODES + n0 + (m >> 1)) * HID;
    FragU af[4];
    if (FP32_IN){
      const float* X = (const float*)Xv;
#pragma unroll
      for (int s = 0; s < 4; s++){
        const float* p = X + ga + s * 32 + kq * 8;
        floatx4 f0 = *((const floatx4*)p);
        floatx4 f1 = *((const floatx4*)(p + 4));
        ushort8 r;
#pragma unroll
        for (int j = 0; j < 4; j++){ r[j] = f2bf(f0[j]); r[j + 4] = f2bf(f1[j]); }
        af[s].u = r;
      }
    } else {
      const uint16_t* X = (const uint16_t*)Xv;
#pragma unroll
      for (int s = 0; s < 4; s++)
        af[s].u = *((const ushort8*)(X + ga + s * 32 + kq * 8));
    }

    floatx4 acc[8];
#pragma unroll
    for (int c = 0; c < 8; c++) acc[c] = floatx4{0.f, 0.f, 0.f, 0.f};
#pragma unroll
    for (int s = 0; s < 4; s++)
#pragma unroll
      for (int c = 0; c < 8; c++)
        acc[c] = __builtin_amdgcn_mfma_f32_16x16x32_bf16(af[s].b, wf[c][s].b, acc[c], 0, 0, 0);

    // C/D: col f = c*16+m, A-row rr = kq*4+i -> node n0+(rr>>1), b=rr&1
    // Y u16 idx = node*256 + (f>>1)*4 + b*2 + (f&1)
#pragma unroll
    for (int c = 0; c < 8; c++)
#pragma unroll
      for (int i = 0; i < 4; i++){
        int rr = kq * 4 + i;
        int node = n0 + (rr >> 1);
        int b = rr & 1;
        Y[(size_t)node * 256 + (size_t)(c * 8 + (m >> 1)) * 4 + b * 2 + (m & 1)] = f2bf(acc[c][i]);
      }
  }
}

// ---------- MFMA classifier: out = h @ WcS + cvec (fp32 out, planar H in) ----------
__global__ __launch_bounds__(256) void k_cls_mfma(const uint16_t* __restrict__ H,
                                                  const uint16_t* __restrict__ WPC,
                                                  const float* __restrict__ cvec,
                                                  float* __restrict__ out){
  const int lane = threadIdx.x & 63;
  const int wid  = threadIdx.x >> 6;
  const int gw   = blockIdx.x * 4 + wid;
  const int nw   = GEMM_BLOCKS * 4;
  const int m    = lane & 15;
  const int kq   = lane >> 4;

  FragU wf[4];
#pragma unroll
  for (int s = 0; s < 4; s++)
    wf[s].u = *((const ushort8*)(WPC + (size_t)((s * 64 + lane) * 8)));
  const float cv = cvec[m];

  for (int t = gw; t < CLS_TILES; t += nw){
    const int row0 = t * 16;
    FragU af[4];
#pragma unroll
    for (int s = 0; s < 4; s++)
      af[s].u = *((const ushort8*)(H + (size_t)(row0 + m) * HID + s * 32 + kq * 8));
    floatx4 acc = floatx4{0.f, 0.f, 0.f, 0.f};
#pragma unroll
    for (int s = 0; s < 4; s++)
      acc = __builtin_amdgcn_mfma_f32_16x16x32_bf16(af[s].b, wf[s].b, acc, 0, 0, 0);
#pragma unroll
    for (int i = 0; i < 4; i++)
      out[(size_t)(row0 + kq * 4 + i) * OUTD + m] = acc[i] + cv;
  }
}

// ---------- aggregation (pair-interleaved XW gather) + rank-1 + bias + relu + BN stats ----------
__global__ __launch_bounds__(256) void k_agg(const uint16_t* __restrict__ XW,
                                             const int* __restrict__ rp,
                                             const unsigned long long* __restrict__ edg,
                                             const float* __restrict__ dinv,
                                             const float* __restrict__ bias,
                                             const float* __restrict__ cvec,
                                             uint16_t* __restrict__ H,
                                             float* __restrict__ psum,
                                             float* __restrict__ pssq){
  __shared__ float lsum[128];
  __shared__ float lssq[128];
  const int tid = threadIdx.x;
  if (tid < 128){ lsum[tid] = 0.f; lssq[tid] = 0.f; }
  __syncthreads();

  const int lane = tid & 63;
  const int wid  = tid >> 6;
  const int gw   = blockIdx.x * 4 + wid;
  const int nw   = AGG_BLOCKS * 4;
  const uint32_t* Xu = (const uint32_t*)XW;   // node block = 128 u32 (pair-interleaved)
  uint32_t* Hu = (uint32_t*)H;
  const int f0 = lane * 2;
  const float b0 = bias[f0], b1 = bias[f0 + 1];
  const float c0 = cvec ? cvec[f0] : 0.f;
  const float c1 = cvec ? cvec[f0 + 1] : 0.f;
  float ts0 = 0.f, ts1 = 0.f, tq0 = 0.f, tq1 = 0.f;

  for (int node = gw; node < N_NODES; node += nw){
    const float di = dinv[node];
    const float sn = di * di;
    const int e0 = rp[node], e1 = rp[node + 1];
    // self row: one dwordx2 gets both batches' feat pair
    uint2 sp = *((const uint2*)(Xu + (size_t)node * 128 + lane * 2));
    float a0x = sn * bf_lo(sp.x), a0y = sn * bf_hi(sp.x);
    float a1x = sn * bf_lo(sp.y), a1y = sn * bf_hi(sp.y);
    float wsum = sn;
    int e = e0;
    // unroll x8: 8 packed edge recs, 8 dwordx2 gathers in flight
    for (; e + 8 <= e1; e += 8){
      unsigned long long rec[8];
#pragma unroll
      for (int u = 0; u < 8; u++) rec[u] = edg[e + u];
      uint2 q[8];
#pragma unroll
      for (int u = 0; u < 8; u++){
        size_t src = (uint32_t)rec[u];
        q[u] = *((const uint2*)(Xu + src * 128 + lane * 2));
      }
#pragma unroll
      for (int u = 0; u < 8; u++){
        float w = __uint_as_float((uint32_t)(rec[u] >> 32));
        a0x = fmaf(w, bf_lo(q[u].x), a0x); a0y = fmaf(w, bf_hi(q[u].x), a0y);
        a1x = fmaf(w, bf_lo(q[u].y), a1x); a1y = fmaf(w, bf_hi(q[u].y), a1y);
        wsum += w;
      }
    }
    for (; e + 4 <= e1; e += 4){
      unsigned long long rec[4];
#pragma unroll
      for (int u = 0; u < 4; u++) rec[u] = edg[e + u];
      uint2 q[4];
#pragma unroll
      for (int u = 0; u < 4; u++){
        size_t src = (uint32_t)rec[u];
        q[u] = *((const uint2*)(Xu + src * 128 + lane * 2));
      }
#pragma unroll
      for (int u = 0; u < 4; u++){
        float w = __uint_as_float((uint32_t)(rec[u] >> 32));
        a0x = fmaf(w, bf_lo(q[u].x), a0x); a0y = fmaf(w, bf_hi(q[u].x), a0y);
        a1x = fmaf(w, bf_lo(q[u].y), a1x); a1y = fmaf(w, bf_hi(q[u].y), a1y);
        wsum += w;
      }
    }
    for (; e < e1; e++){
      unsigned long long rec = edg[e];
      size_t src = (uint32_t)rec;
      float w = __uint_as_float((uint32_t)(rec >> 32));
      uint2 q = *((const uint2*)(Xu + src * 128 + lane * 2));
      a0x = fmaf(w, bf_lo(q.x), a0x); a0y = fmaf(w, bf_hi(q.x), a0y);
      a1x = fmaf(w, bf_lo(q.y), a1x); a1y = fmaf(w, bf_hi(q.y), a1y);
      wsum += w;
    }
    // rank-1 BN-fold term + bias + relu
    a0x = fmaxf(fmaf(wsum, c0, a0x) + b0, 0.f); a0y = fmaxf(fmaf(wsum, c1, a0y) + b1, 0.f);
    a1x = fmaxf(fmaf(wsum, c0, a1x) + b0, 0.f); a1y = fmaxf(fmaf(wsum, c1, a1y) + b1, 0.f);
    // H stays planar [b][node][feat]
    Hu[(size_t)node * 64 + lane]             = (uint32_t)f2bf(a0x) | ((uint32_t)f2bf(a0y) << 16);
    Hu[(size_t)(N_NODES + node) * 64 + lane] = (uint32_t)f2bf(a1x) | ((uint32_t)f2bf(a1y) << 16);
    ts0 += a0x + a1x; ts1 += a0y + a1y;
    tq0 += a0x * a0x + a1x * a1x; tq1 += a0y * a0y + a1y * a1y;
  }

  atomicAdd(&lsum[f0],     ts0); atomicAdd(&lsum[f0 + 1], ts1);
  atomicAdd(&lssq[f0],     tq0); atomicAdd(&lssq[f0 + 1], tq1);
  __syncthreads();
  if (tid < 128){
    psum[(size_t)blockIdx.x * 128 + tid] = lsum[tid];
    pssq[(size_t)blockIdx.x * 128 + tid] = lssq[tid];
  }
}

// ---------- BN mid-reduction: 2048 partial rows -> 32 ----------
__global__ __launch_bounds__(256) void k_bnmid(const float* __restrict__ psum,
                                               const float* __restrict__ pssq,
                                               float* __restrict__ msum,
                                               float* __restrict__ mssq){
  __shared__ float ss[2][128];
  __shared__ float sq[2][128];
  const int tid = threadIdx.x;
  const int f  = tid & 127;
  const int sl = tid >> 7;
  const int rows_per = AGG_BLOCKS / MID_BLOCKS;  // 64
  const int base = blockIdx.x * rows_per;
  float s = 0.f, q = 0.f;
  for (int r = base + sl; r < base + rows_per; r += 2){
    s += psum[(size_t)r * 128 + f];
    q += pssq[(size_t)r * 128 + f];
  }
  ss[sl][f] = s; sq[sl][f] = q;
  __syncthreads();
  if (tid < 128){
    msum[(size_t)blockIdx.x * 128 + tid] = ss[0][tid] + ss[1][tid];
    mssq[(size_t)blockIdx.x * 128 + tid] = sq[0][tid] + sq[1][tid];
  }
}

// ---------- BN finalize ----------
__global__ __launch_bounds__(128) void k_bnfin(const float* __restrict__ msum,
                                               const float* __restrict__ mssq,
                                               const float* __restrict__ gamma,
                                               const float* __restrict__ beta,
                                               float* __restrict__ sca,
                                               float* __restrict__ shf){
  const int f = threadIdx.x;
  float S = 0.f, Q = 0.f;
#pragma unroll
  for (int b = 0; b < MID_BLOCKS; b++){
    S += msum[(size_t)b * 128 + f];
    Q += mssq[(size_t)b * 128 + f];
  }
  const float inv = 1.0f / (float)ROWS;
  float mu = S * inv;
  float var = fmaxf(Q * inv - mu * mu, 0.f);
  float rstd = 1.0f / sqrtf(var + 1e-5f);
  float sc = gamma[f] * rstd;
  sca[f] = sc;
  shf[f] = fmaf(-mu, sc, beta[f]);
}

// ---------- launch ----------
extern "C" void kernel_launch(void* const* d_in, const int* in_sizes, int n_in,
                              void* d_out, int out_size, void* d_ws, size_t ws_size,
                              hipStream_t stream){
  const float* x   = (const float*)d_in[0];
  const int*   ei  = (const int*)d_in[1];
  const float* ewp = (const float*)d_in[2];
  const float* W1  = (const float*)d_in[3];
  const float* b1  = (const float*)d_in[4];
  const float* W2  = (const float*)d_in[5];
  const float* b2  = (const float*)d_in[6];
  const float* g1  = (const float*)d_in[7];
  const float* be1 = (const float*)d_in[8];
  const float* g2  = (const float*)d_in[9];
  const float* be2 = (const float*)d_in[10];
  const float* Wc  = (const float*)d_in[11];
  const float* bc  = (const float*)d_in[12];
  float* out = (float*)d_out;

  char* wsb = (char*)d_ws;
  size_t off = 0;
  auto give = [&](size_t bytes) -> void* {
    void* p = wsb + off;
    off = (off + bytes + 255) & ~(size_t)255;
    return p;
  };
  uint16_t* XW  = (uint16_t*)give((size_t)ROWS * 128 * 2);   // pair-interleaved
  uint16_t* Hb  = (uint16_t*)give((size_t)ROWS * 128 * 2);   // planar
  unsigned long long* DC  = (unsigned long long*)give((size_t)N_NODES * 8);
  unsigned long long* EDG = (unsigned long long*)give((size_t)N_EDGES * 8);
  unsigned int* SLOT = (unsigned int*)give((size_t)N_EDGES * 4);
  float* DINV   = (float*)give((size_t)N_NODES * 4);
  int*   RP     = (int*)give((size_t)(N_NODES + 1) * 4);
  int*   BSUM   = (int*)give(1024);
  float* PSUM   = (float*)give((size_t)AGG_BLOCKS * 128 * 4);
  float* PSSQ   = (float*)give((size_t)AGG_BLOCKS * 128 * 4);
  float* MSUM   = (float*)give((size_t)MID_BLOCKS * 128 * 4);
  float* MSSQ   = (float*)give((size_t)MID_BLOCKS * 128 * 4);
  float* SCA1   = (float*)give(512);
  float* SHF1   = (float*)give(512);
  float* SCA2   = (float*)give(512);
  float* SHF2   = (float*)give(512);
  uint16_t* WP1 = (uint16_t*)give((size_t)HID * HID * 2);
  uint16_t* WP2 = (uint16_t*)give((size_t)HID * HID * 2);
  uint16_t* WPC = (uint16_t*)give((size_t)HID * OUTD * 2);
  float* C2     = (float*)give(512);
  float* CVC    = (float*)give(64);
  (void)ws_size; (void)n_in; (void)in_sizes; (void)out_size;

  const int nb_nodes = (N_NODES + 255) / 256;   // 196
  const int nb_edges = (N_EDGES + 255) / 256;   // 2500

  k_init<<<nb_nodes, 256, 0, stream>>>(DC);
  k_edge1<<<nb_edges, 256, 0, stream>>>(ei, ewp, DC, SLOT);
  k_scan_bsum<<<SCAN_BLOCKS, 256, 0, stream>>>(DC, BSUM, DINV);
  k_scan_excl<<<1, 256, 0, stream>>>(BSUM);
  k_scan_write<<<SCAN_BLOCKS, 256, 0, stream>>>(DC, BSUM, RP);
  k_fill<<<nb_edges, 256, 0, stream>>>(ei, ewp, DINV, SLOT, RP, EDG);
  k_wpack<<<8, 256, 0, stream>>>(W1, nullptr, WP1);

  // layer 1: xw1 = bf16(x) @ W1  (pair-interleaved out)
  k_gemm_mfma<true><<<GEMM_BLOCKS, 256, 0, stream>>>(x, WP1, XW);
  k_agg<<<AGG_BLOCKS, 256, 0, stream>>>(XW, RP, EDG, DINV, b1, nullptr, Hb, PSUM, PSSQ);
  k_bnmid<<<MID_BLOCKS, 256, 0, stream>>>(PSUM, PSSQ, MSUM, MSSQ);
  k_bnfin<<<1, 128, 0, stream>>>(MSUM, MSSQ, g1, be1, SCA1, SHF1);

  // layer 2: bn1 folded -> W2' = s1 (.) W2, c2 = t1 @ W2 (applied via wsum in agg)
  k_wpack<<<8, 256, 0, stream>>>(W2, SCA1, WP2);
  k_cvec<<<1, 128, 0, stream>>>(SHF1, W2, nullptr, C2, HID, HID);
  k_gemm_mfma<false><<<GEMM_BLOCKS, 256, 0, stream>>>(Hb, WP2, XW);
  k_agg<<<AGG_BLOCKS, 256, 0, stream>>>(XW, RP, EDG, DINV, b2, C2, Hb, PSUM, PSSQ);
  k_bnmid<<<MID_BLOCKS, 256, 0, stream>>>(PSUM, PSSQ, MSUM, MSSQ);
  k_bnfin<<<1, 128, 0, stream>>>(MSUM, MSSQ, g2, be2, SCA2, SHF2);

  // classifier: bn2 folded -> WcS = s2 (.) Wc, cvec = t2 @ Wc + bc
  k_wpackc<<<1, 256, 0, stream>>>(Wc, SCA2, WPC);
  k_cvec<<<1, 128, 0, stream>>>(SHF2, Wc, bc, CVC, OUTD, OUTD);
  k_cls_mfma<<<GEMM_BLOCKS, 256, 0, stream>>>(Hb, WPC, CVC, out);
}